// Round 15
// baseline (213.605 us; speedup 1.0000x reference)
//
#include <hip/hip_runtime.h>
#include <hip/hip_bf16.h>

typedef short s16x8 __attribute__((ext_vector_type(8)));
typedef float f32x4 __attribute__((ext_vector_type(4)));
typedef float f32x16 __attribute__((ext_vector_type(16)));
typedef unsigned short u16x4 __attribute__((ext_vector_type(4)));
typedef unsigned u32x4 __attribute__((ext_vector_type(4)));

#define DEV static __device__ __forceinline__

DEV unsigned short f2bf(float f) {  // native cast -> compiler packs pairs into v_cvt_pk_bf16_f32
  __hip_bfloat16 h = __float2bfloat16(f);
  return *reinterpret_cast<unsigned short*>(&h);
}
DEV float bf2f(unsigned short u) {
  union { unsigned u; float f; } v; v.u = (unsigned)u << 16; return v.f;
}

#define GLDS16(src, dst) \
  __builtin_amdgcn_global_load_lds((const __attribute__((address_space(1))) void*)(src), \
                                   (__attribute__((address_space(3))) void*)(dst), 16, 0, 0)

#define MFMA(a, b, c) __builtin_amdgcn_mfma_f32_16x16x32_bf16((a), (b), (c), 0, 0, 0)
#define MFMA32(a, b, c) __builtin_amdgcn_mfma_f32_32x32x16_bf16((a), (b), (c), 0, 0, 0)

// ---------------- elementwise fp32 -> bf16 ----------------
__global__ __launch_bounds__(256) void k_f32_to_bf16(const float* __restrict__ in,
                                                     unsigned short* __restrict__ out, int n4) {
  int i = blockIdx.x * 256 + threadIdx.x;
  if (i >= n4) return;
  float4 v = ((const float4*)in)[i];
  u16x4 o; o.x = f2bf(v.x); o.y = f2bf(v.y); o.z = f2bf(v.z); o.w = f2bf(v.w);
  ((u16x4*)out)[i] = o;
}

// ---------------- weight transpose+convert: (K,N) f32 -> (N,K) bf16, with scale ----------------
__global__ __launch_bounds__(256) void k_transpose_w(const float* __restrict__ W,
                                                     unsigned short* __restrict__ Wt,
                                                     int K, int N, float scale) {
  __shared__ float t[64][65];
  int k0 = blockIdx.x * 64, n0 = blockIdx.y * 64;
  int tid = threadIdx.x;
#pragma unroll
  for (int i = 0; i < 16; ++i) {
    int idx = tid + i * 256; int r = idx >> 6, c = idx & 63;
    t[r][c] = W[(size_t)(k0 + r) * N + (n0 + c)];
  }
  __syncthreads();
#pragma unroll
  for (int i = 0; i < 16; ++i) {
    int idx = tid + i * 256; int r = idx >> 6, c = idx & 63;
    Wt[(size_t)(n0 + r) * K + (k0 + c)] = f2bf(t[c][r] * scale);
  }
}

// QKV fused variant: z selects {wq, wk, wv}; 1024x1024 each; wq gets scale.
__global__ __launch_bounds__(256) void k_transpose_w3(
    const float* __restrict__ W0, const float* __restrict__ W1,
    const float* __restrict__ W2, unsigned short* __restrict__ Wt, float s0) {
  __shared__ float t[64][65];
  int z = blockIdx.z;
  const float* W = (z == 0) ? W0 : (z == 1) ? W1 : W2;
  float scale = (z == 0) ? s0 : 1.0f;
  unsigned short* dst = Wt + (size_t)z * 1024 * 1024;
  int k0 = blockIdx.x * 64, n0 = blockIdx.y * 64;
  int tid = threadIdx.x;
#pragma unroll
  for (int i = 0; i < 16; ++i) {
    int idx = tid + i * 256; int r = idx >> 6, c = idx & 63;
    t[r][c] = W[(size_t)(k0 + r) * 1024 + (n0 + c)];
  }
  __syncthreads();
#pragma unroll
  for (int i = 0; i < 16; ++i) {
    int idx = tid + i * 256; int r = idx >> 6, c = idx & 63;
    dst[(size_t)(n0 + r) * 1024 + (k0 + c)] = f2bf(t[c][r] * scale);
  }
}

// ---------------- concat 3 bias vectors (a gets scale) ----------------
__global__ void k_concat3(const float* __restrict__ a, const float* __restrict__ b,
                          const float* __restrict__ c, float* __restrict__ out, int n, float sa) {
  int i = blockIdx.x * 256 + threadIdx.x;
  if (i >= 3 * n) return;
  int j = (i < n) ? i : (i < 2 * n ? i - n : i - 2 * n);
  out[i] = (i < n) ? a[j] * sa : (i < 2 * n ? b[j] : c[j]);
}

// ---------------- 256x256 4-phase pipelined GEMM ----------------
// BK=64, two k-half granules, 2 LDS tile-buffers, counted vmcnt(4), setprio
// clusters, XOR-swizzled LDS (both-sides), XCD block swizzle. BOTH fragment
// bubbles removed: k1(t) frags read before the mid barrier (resident since
// tile entry); k0(t+1) mh0+B frags read during ph3/ph4 (resident after mid
// vmcnt(4)+barrier; region next rewritten only after its consuming MFMA).
// mh1-k0 read at ph1 under the ph1 MFMA cluster.
// MODE 0: bias->bf16. MODE 1: bias+relu->bf16. MODE 3: raw bf16 partial at
// Cb + z*zstride. MODE 4: QKV split: nt<4 -> Cq, nt<8 -> Ck, else V scattered
// transposed into Cv[bh][d][sigma(s)] (sigma = swap bits 2<->3 of s%16).
template <int MODE>
__global__ __launch_bounds__(512, 2) void k_gemm8(
    const unsigned short* __restrict__ A, int lda,
    const unsigned short* __restrict__ Bt, int ldb,
    const float* __restrict__ bias,
    unsigned short* __restrict__ Cb, float* __restrict__ Cf, int ldc,
    int K, int nnt, size_t zstride,
    unsigned short* __restrict__ Cq, unsigned short* __restrict__ Ck,
    unsigned short* __restrict__ Cv) {
  __shared__ __align__(16) unsigned short As[2 * 2 * 8192];  // [buf][kh][256][32]
  __shared__ __align__(16) unsigned short Bs[2 * 2 * 8192];
  int nwg = gridDim.x;
  int bid = blockIdx.x;
  int cpx = nwg >> 3;
  int swz = (bid & 7) * cpx + (bid >> 3);
  int mt = swz / nnt, nt = swz % nnt;
  int m0 = mt * 256, n0 = nt * 256;
  int tid = threadIdx.x, w = tid >> 6, l = tid & 63;
  int wm = (w >> 2) * 128, wn = (w & 3) * 64;
  int kb = blockIdx.z * K;

  int sr = tid >> 2;
  int gsrc = (tid & 3) ^ ((sr >> 1) & 3);
  const unsigned short* Ag0 = A + (size_t)(m0 + sr) * lda + kb + gsrc * 8;
  const unsigned short* Ag1 = Ag0 + (size_t)128 * lda;
  const unsigned short* Bg0 = Bt + (size_t)(n0 + sr) * ldb + kb + gsrc * 8;
  const unsigned short* Bg1 = Bg0 + (size_t)128 * ldb;

#define STG_A(t, kh) do { int _c = (t) * 64 + (kh) * 32; int _d = ((((t) & 1) * 2 + (kh)) * 8192); \
    GLDS16(Ag0 + _c, &As[_d + tid * 8]); GLDS16(Ag1 + _c, &As[_d + 4096 + tid * 8]); } while (0)
#define STG_B(t, kh) do { int _c = (t) * 64 + (kh) * 32; int _d = ((((t) & 1) * 2 + (kh)) * 8192); \
    GLDS16(Bg0 + _c, &Bs[_d + tid * 8]); GLDS16(Bg1 + _c, &Bs[_d + 4096 + tid * 8]); } while (0)

  int lswz = (l >> 1) & 3;
  int acol = ((l >> 4) ^ lswz) * 8;
  const unsigned short* Afr = &As[(wm + (l & 15)) * 32 + acol];
  const unsigned short* Bfr = &Bs[(wn + (l & 15)) * 32 + acol];

  f32x4 acc[8][4] = {};
  int nkt = K >> 6;

  STG_A(0, 0); STG_B(0, 0); STG_A(0, 1); STG_B(0, 1); STG_A(1, 0); STG_B(1, 0);
  asm volatile("s_waitcnt vmcnt(4)" ::: "memory");
  __builtin_amdgcn_s_barrier();
  __builtin_amdgcn_sched_barrier(0);

  // loop-carried preload: k0(t) mh0 + B fragments (tile 0 resident after prologue)
  s16x8 af2[4], bf2[4];
#pragma unroll
  for (int nr = 0; nr < 4; ++nr) bf2[nr] = *(const s16x8*)(Bfr + nr * 512);
#pragma unroll
  for (int mr = 0; mr < 4; ++mr) af2[mr] = *(const s16x8*)(Afr + mr * 512);

  for (int t = 0; t < nkt; ++t) {
    int cur = t & 1, rem = nkt - t;
    const unsigned short* ab = Afr + cur * 16384;
    const unsigned short* bb = Bfr + cur * 16384;
    s16x8 af[4], afn[4], bfn[4], afm[4];
    // ---- p1: (mhalf0, k0) from preloaded af2/bf2; issue mh1-k0 reads under cluster ----
    if (t + 1 < nkt) STG_A(t + 1, 1);
#pragma unroll
    for (int mr = 0; mr < 4; ++mr) af[mr] = *(const s16x8*)(ab + 2048 + mr * 512);
    __builtin_amdgcn_s_setprio(1);
#pragma unroll
    for (int mr = 0; mr < 4; ++mr)
#pragma unroll
      for (int nr = 0; nr < 4; ++nr)
        acc[mr][nr] = MFMA(af2[mr], bf2[nr], acc[mr][nr]);
    __builtin_amdgcn_s_setprio(0);
    // ---- p2: (mhalf1, k0) ----
    if (t + 1 < nkt) STG_B(t + 1, 1);
    __builtin_amdgcn_s_setprio(1);
#pragma unroll
    for (int mr = 0; mr < 4; ++mr)
#pragma unroll
      for (int nr = 0; nr < 4; ++nr)
        acc[mr + 4][nr] = MFMA(af[mr], bf2[nr], acc[mr + 4][nr]);
    __builtin_amdgcn_s_setprio(0);
    // ---- prefetch k1(t) fragments (resident since tile entry) ----
#pragma unroll
    for (int nr = 0; nr < 4; ++nr) bfn[nr] = *(const s16x8*)(bb + 8192 + nr * 512);
#pragma unroll
    for (int mr = 0; mr < 4; ++mr) afn[mr] = *(const s16x8*)(ab + 8192 + mr * 512);
#pragma unroll
    for (int mr = 0; mr < 4; ++mr) afm[mr] = *(const s16x8*)(ab + 8192 + 2048 + mr * 512);
    if (rem >= 2) { asm volatile("s_waitcnt vmcnt(4)" ::: "memory"); }
    else          { asm volatile("s_waitcnt vmcnt(0)" ::: "memory"); }
    __builtin_amdgcn_s_barrier();
    // ---- p3: (mhalf0, k1); preload k0(t+1) B frags (resident after mid barrier) ----
    if (t + 2 < nkt) STG_A(t + 2, 0);
    if (t + 1 < nkt) {
      const unsigned short* bbn = Bfr + (cur ^ 1) * 16384;
#pragma unroll
      for (int nr = 0; nr < 4; ++nr) bf2[nr] = *(const s16x8*)(bbn + nr * 512);
    }
    __builtin_amdgcn_s_setprio(1);
#pragma unroll
    for (int mr = 0; mr < 4; ++mr)
#pragma unroll
      for (int nr = 0; nr < 4; ++nr)
        acc[mr][nr] = MFMA(afn[mr], bfn[nr], acc[mr][nr]);
    __builtin_amdgcn_s_setprio(0);
    // ---- p4: (mhalf1, k1); preload k0(t+1) mh0 frags ----
    if (t + 2 < nkt) STG_B(t + 2, 0);
    if (t + 1 < nkt) {
      const unsigned short* abn = Afr + (cur ^ 1) * 16384;
#pragma unroll
      for (int mr = 0; mr < 4; ++mr) af2[mr] = *(const s16x8*)(abn + mr * 512);
    }
    __builtin_amdgcn_s_setprio(1);
#pragma unroll
    for (int mr = 0; mr < 4; ++mr)
#pragma unroll
      for (int nr = 0; nr < 4; ++nr)
        acc[mr + 4][nr] = MFMA(afm[mr], bfn[nr], acc[mr + 4][nr]);
    __builtin_amdgcn_s_setprio(0);
    if (rem >= 3) { asm volatile("s_waitcnt vmcnt(4)" ::: "memory"); }
    else          { asm volatile("s_waitcnt vmcnt(0)" ::: "memory"); }
    __builtin_amdgcn_s_barrier();
    __builtin_amdgcn_sched_barrier(0);
  }
#undef STG_A
#undef STG_B

  if (MODE == 4) {
    if (nt < 8) {
      unsigned short* dst = (nt < 4) ? Cq : Ck;
      int cb = (nt < 4) ? 0 : 1024;
#pragma unroll
      for (int mr = 0; mr < 8; ++mr) {
        int rb = m0 + wm + mr * 16 + (l >> 4) * 4;
#pragma unroll
        for (int nr = 0; nr < 4; ++nr) {
          int col = n0 + wn + nr * 16 + (l & 15);
          float bv = bias[col];
#pragma unroll
          for (int j = 0; j < 4; ++j)
            dst[(size_t)(rb + j) * 1024 + (col - cb)] = f2bf(acc[mr][nr][j] + bv);
        }
      }
    } else {  // V: scatter transposed into Cv[bh][d][sigma(s)], sigma = swap bits 2<->3
#pragma unroll
      for (int mr = 0; mr < 8; ++mr) {
        int rb = m0 + wm + mr * 16 + (l >> 4) * 4;
        int b2 = rb >> 11, s2 = rb & 2047;
        int s2p = (s2 & ~12) | ((s2 & 4) << 1) | ((s2 & 8) >> 1);
#pragma unroll
        for (int nr = 0; nr < 4; ++nr) {
          int col2 = n0 - 2048 + wn + nr * 16 + (l & 15);
          float bv = bias[col2 + 2048];
          u16x4 pk;
#pragma unroll
          for (int j = 0; j < 4; ++j) ((unsigned short*)&pk)[j] = f2bf(acc[mr][nr][j] + bv);
          *(u16x4*)(Cv + ((size_t)((b2 * 16 + (col2 >> 6)) * 64 + (col2 & 63))) * 2048 + s2p) = pk;
        }
      }
    }
    return;
  }
  unsigned short* Cbz = (MODE == 3) ? (Cb + zstride * blockIdx.z) : Cb;
#pragma unroll
  for (int mr = 0; mr < 8; ++mr) {
    int rb = m0 + wm + mr * 16 + (l >> 4) * 4;
#pragma unroll
    for (int nr = 0; nr < 4; ++nr) {
      int col = n0 + wn + nr * 16 + (l & 15);
      float bv = (MODE == 3) ? 0.f : bias[col];
#pragma unroll
      for (int j = 0; j < 4; ++j) {
        float v = acc[mr][nr][j] + bv;
        size_t off = (size_t)(rb + j) * ldc + col;
        if (MODE == 1) v = fmaxf(v, 0.f);
        Cbz[off] = f2bf(v);
      }
    }
  }
}

// ---------------- FF2 split-K=4 reduce (row-interleaved bf16 slices) ----------------
__global__ __launch_bounds__(256) void k_ff2_reduce(
    unsigned short* __restrict__ slices, const float* __restrict__ bias,
    const unsigned short* __restrict__ resid, float* __restrict__ partials) {
  __shared__ float red[8];
  int i = blockIdx.x;
  size_t rb = (size_t)i * 4096;
  int c = threadIdx.x * 4;
  u16x4 a0 = *(const u16x4*)(slices + rb + c);
  u16x4 a1 = *(const u16x4*)(slices + rb + 1024 + c);
  u16x4 a2 = *(const u16x4*)(slices + rb + 2048 + c);
  u16x4 a3 = *(const u16x4*)(slices + rb + 3072 + c);
  float4 bv = *(const float4*)(bias + c);
  u16x4 rv = *(const u16x4*)(resid + (size_t)i * 1024 + c);
  float4 o;
  o.x = bf2f(a0.x) + bf2f(a1.x) + bf2f(a2.x) + bf2f(a3.x) + bv.x + bf2f(rv.x);
  o.y = bf2f(a0.y) + bf2f(a1.y) + bf2f(a2.y) + bf2f(a3.y) + bv.y + bf2f(rv.y);
  o.z = bf2f(a0.z) + bf2f(a1.z) + bf2f(a2.z) + bf2f(a3.z) + bv.z + bf2f(rv.z);
  o.w = bf2f(a0.w) + bf2f(a1.w) + bf2f(a2.w) + bf2f(a3.w) + bv.w + bf2f(rv.w);
  __syncthreads();
  *(float4*)((float*)slices + (size_t)i * 2048 + c) = o;
  float bsum = o.x + o.y + o.z + o.w;
  float bsq = o.x * o.x + o.y * o.y + o.z * o.z + o.w * o.w;
  int wv = threadIdx.x >> 6, lv = threadIdx.x & 63;
#pragma unroll
  for (int mk = 1; mk < 64; mk <<= 1) { bsum += __shfl_xor(bsum, mk); bsq += __shfl_xor(bsq, mk); }
  if (lv == 0) { red[wv] = bsum; red[4 + wv] = bsq; }
  __syncthreads();
  if (threadIdx.x == 0) {
    partials[i * 2] = red[0] + red[1] + red[2] + red[3];
    partials[i * 2 + 1] = red[4] + red[5] + red[6] + red[7];
  }
}

// ---------------- causal flash attention, QBLK=128 (4 waves), 32x32 MFMA ----------------
// (round-14 proven: K/V staged once per block serve 4 waves; QK(T) ||
// softmax+PV(T-1) pipeline, top vmcnt(2), swapped QK, sigma-stored V,
// defer-max, log2-domain exp; qt-perm balances CU pairs.)
__global__ __launch_bounds__(256, 2) void k_attn(
    const unsigned short* __restrict__ Qg, const unsigned short* __restrict__ Kg,
    const unsigned short* __restrict__ Vt,
    const float* __restrict__ x, unsigned short* __restrict__ hpre,
    float* __restrict__ partials, int S, int H) {
  __shared__ __align__(16) unsigned short Ks[2][4096];
  __shared__ __align__(16) unsigned short Vs[2][4096];
  __shared__ float ascr[4][32];
  __shared__ float red[8];
  int bh = blockIdx.x, b = bh >> 4, h = bh & 15;
  int y = (int)blockIdx.y;
  int qt = (y < 8) ? (15 - y) : (y - 8);
  int tid = threadIdx.x, w = tid >> 6, l = tid & 63;
  int lo = l & 31, hi5 = l >> 5;
  const int U = H * 64;
  const unsigned short* Qb = Qg + (size_t)(b * S) * 1024 + h * 64;
  const unsigned short* Kb = Kg + (size_t)(b * S) * 1024 + h * 64;
  const unsigned short* Vb = Vt + (size_t)bh * 64 * S;
  int tl = 2 * qt + 1;

  int sg_r[2], sg_c[2];
#pragma unroll
  for (int it = 0; it < 2; ++it) {
    int g = it * 256 + tid;
    sg_r[it] = g >> 3;
    sg_c[it] = ((g & 7) ^ ((g >> 3) & 7)) * 8;
  }
#define STG_K(kt) do { int _kn = (kt) * 64, _bf = (kt) & 1; \
    _Pragma("unroll") for (int it = 0; it < 2; ++it) \
      GLDS16(Kb + (size_t)(_kn + sg_r[it]) * 1024 + sg_c[it], &Ks[_bf][(it * 256 + tid) * 8]); } while (0)
#define STG_V(kt) do { int _kn = (kt) * 64, _bf = (kt) & 1; \
    _Pragma("unroll") for (int it = 0; it < 2; ++it) \
      GLDS16(Vb + (size_t)sg_r[it] * S + _kn + sg_c[it], &Vs[_bf][(it * 256 + tid) * 8]); } while (0)

  int qrow = qt * 128 + w * 32 + lo;
  s16x8 qf[4];
#pragma unroll
  for (int s = 0; s < 4; ++s)
    qf[s] = *(const s16x8*)(Qb + (size_t)qrow * 1024 + s * 16 + hi5 * 8);

  int krow[16];
#pragma unroll
  for (int r = 0; r < 16; ++r) krow[r] = (r & 3) + 8 * (r >> 2) + 4 * hi5;
  int wq = w * 32 + lo;

  f32x16 o0 = {}, o1 = {};
  float m = -1e30f, lsum = 0.f;
  f32x16 scA0, scA1, scB0, scB1;

#define MBASE(T) (((T) >= 2 * qt) ? ((T) * 64 - qt * 128) : -1)

#define QK_T(S0, S1, T) do { \
    S0 = (f32x16)(0.0f); S1 = (f32x16)(0.0f); \
    const unsigned short* _kp = &Ks[(T) & 1][0]; \
    __builtin_amdgcn_s_setprio(1); \
    _Pragma("unroll") for (int s = 0; s < 4; ++s) { \
      int gc = ((2 * s + hi5) ^ (lo & 7)) * 8; \
      s16x8 kf0 = *(const s16x8*)&_kp[lo * 64 + gc]; \
      s16x8 kf1 = *(const s16x8*)&_kp[(32 + lo) * 64 + gc]; \
      S0 = MFMA32(kf0, qf[s], S0); \
      S1 = MFMA32(kf1, qf[s], S1); } \
    __builtin_amdgcn_s_setprio(0); } while (0)

#define SMPV(S0, S1, T, MB) do { \
    if ((MB) >= 0) { \
      _Pragma("unroll") for (int r = 0; r < 16; ++r) { \
        if (krow[r] + (MB) > wq) S0[r] = -1e30f; \
        if (krow[r] + 32 + (MB) > wq) S1[r] = -1e30f; } } \
    float mx = S0[0]; \
    _Pragma("unroll") for (int r = 1; r < 16; ++r) mx = fmaxf(mx, S0[r]); \
    _Pragma("unroll") for (int r = 0; r < 16; ++r) mx = fmaxf(mx, S1[r]); \
    mx = fmaxf(mx, __shfl_xor(mx, 32)); \
    if (__ballot(mx > m + 11.5415603f)) { \
      float mnew = fmaxf(m, mx); \
      float alpha = __builtin_amdgcn_exp2f(m - mnew); \
      m = mnew; lsum *= alpha; \
      if (l < 32) ascr[w][lo] = alpha; \
      _Pragma("unroll") for (int r = 0; r < 16; ++r) { \
        float aj = ascr[w][krow[r]]; o0[r] *= aj; o1[r] *= aj; } } \
    float rs = 0.f; unsigned wk0[8], wk1[8]; \
    _Pragma("unroll") for (int j = 0; j < 8; ++j) { \
      float p0 = __builtin_amdgcn_exp2f(S0[2 * j] - m); \
      float p1 = __builtin_amdgcn_exp2f(S0[2 * j + 1] - m); \
      rs += p0 + p1; wk0[j] = (unsigned)f2bf(p0) | ((unsigned)f2bf(p1) << 16); \
      float p2 = __builtin_amdgcn_exp2f(S1[2 * j] - m); \
      float p3 = __builtin_amdgcn_exp2f(S1[2 * j + 1] - m); \
      rs += p2 + p3; wk1[j] = (unsigned)f2bf(p2) | ((unsigned)f2bf(p3) << 16); } \
    rs += __shfl_xor(rs, 32); lsum += rs; \
    __builtin_amdgcn_s_setprio(1); \
    _Pragma("unroll") for (int s = 0; s < 4; ++s) { \
      u32x4 paw; \
      if (s == 0)      { paw.x = wk0[0]; paw.y = wk0[1]; paw.z = wk0[2]; paw.w = wk0[3]; } \
      else if (s == 1) { paw.x = wk0[4]; paw.y = wk0[5]; paw.z = wk0[6]; paw.w = wk0[7]; } \
      else if (s == 2) { paw.x = wk1[0]; paw.y = wk1[1]; paw.z = wk1[2]; paw.w = wk1[3]; } \
      else             { paw.x = wk1[4]; paw.y = wk1[5]; paw.z = wk1[6]; paw.w = wk1[7]; } \
      s16x8 pa = *(s16x8*)&paw; \
      int gc = ((2 * s + hi5) ^ (lo & 7)) * 8; \
      s16x8 vf0 = *(const s16x8*)&Vs[(T) & 1][lo * 64 + gc]; \
      s16x8 vf1 = *(const s16x8*)&Vs[(T) & 1][(32 + lo) * 64 + gc]; \
      o0 = MFMA32(pa, vf0, o0); \
      o1 = MFMA32(pa, vf1, o1); } \
    __builtin_amdgcn_s_setprio(0); \
  } while (0)

#define BODY(O0, O1, I0, I1, T) do { \
    asm volatile("s_waitcnt vmcnt(2)" ::: "memory"); \
    __builtin_amdgcn_s_barrier(); \
    __builtin_amdgcn_sched_barrier(0); \
    if ((T) + 1 <= tl) STG_K((T) + 1); \
    QK_T(O0, O1, (T)); \
    SMPV(I0, I1, (T) - 1, MBASE((T) - 1)); \
    asm volatile("s_waitcnt lgkmcnt(0)" ::: "memory"); \
    __builtin_amdgcn_sched_barrier(0); \
    __builtin_amdgcn_s_barrier(); \
    __builtin_amdgcn_sched_barrier(0); \
    if ((T) + 1 <= tl) STG_V((T) + 1); \
  } while (0)

  STG_K(0); STG_V(0); STG_K(1); STG_V(1);
  asm volatile("s_waitcnt vmcnt(4)" ::: "memory");
  __builtin_amdgcn_s_barrier();
  __builtin_amdgcn_sched_barrier(0);
  QK_T(scA0, scA1, 0);
  asm volatile("s_waitcnt lgkmcnt(0)" ::: "memory");
  __builtin_amdgcn_sched_barrier(0);

  int t = 1;
  for (; t + 1 <= tl; t += 2) {
    BODY(scB0, scB1, scA0, scA1, t);
    BODY(scA0, scA1, scB0, scB1, t + 1);
  }
  if (t <= tl) {
    BODY(scB0, scB1, scA0, scA1, t);
    asm volatile("s_waitcnt vmcnt(0)" ::: "memory");
    __builtin_amdgcn_sched_barrier(0);
    SMPV(scB0, scB1, tl, MBASE(tl));
  } else {
    asm volatile("s_waitcnt vmcnt(0)" ::: "memory");
    __builtin_amdgcn_sched_barrier(0);
    SMPV(scA0, scA1, tl, MBASE(tl));
  }

  // ---- epilogue: O/l + x residual -> bf16, LN partials ----
  if (l < 32) ascr[w][lo] = 1.f / lsum;
  float bsum = 0.f, bsq = 0.f;
  unsigned short* hb = hpre + (size_t)(b * S) * U + h * 64;
  const float* xb = x + (size_t)(b * S) * U + h * 64;
#pragma unroll
  for (int r = 0; r < 16; ++r) {
    float inv = ascr[w][krow[r]];
    int srow = qt * 128 + w * 32 + krow[r];
    size_t base = (size_t)srow * U + lo;
    float v0 = o0[r] * inv + xb[base];
    float v1 = o1[r] * inv + xb[base + 32];
    hb[base] = f2bf(v0);
    hb[base + 32] = f2bf(v1);
    bsum += v0 + v1; bsq += v0 * v0 + v1 * v1;
  }
#pragma unroll
  for (int mk = 1; mk < 64; mk <<= 1) { bsum += __shfl_xor(bsum, mk); bsq += __shfl_xor(bsq, mk); }
  if (l == 0) { red[w * 2] = bsum; red[w * 2 + 1] = bsq; }
  __syncthreads();
  if (tid == 0) {
    int pi = b * (H * 16) + h * 16 + qt;
    partials[pi * 2] = red[0] + red[2] + red[4] + red[6];
    partials[pi * 2 + 1] = red[1] + red[3] + red[5] + red[7];
  }
#undef STG_K
#undef STG_V
#undef QK_T
#undef SMPV
#undef BODY
#undef MBASE
}

// ---------------- LN over (S,U) per batch ----------------
__global__ __launch_bounds__(256) void k_ln_stats(const float* __restrict__ partials, int nper,
                                                  float* __restrict__ stats, float invN) {
  int b = blockIdx.x, tid = threadIdx.x;
  float s = 0.f, q = 0.f;
  for (int i = tid; i < nper; i += 256) { s += partials[(b * nper + i) * 2]; q += partials[(b * nper + i) * 2 + 1]; }
#pragma unroll
  for (int mk = 1; mk < 64; mk <<= 1) { s += __shfl_xor(s, mk); q += __shfl_xor(q, mk); }
  __shared__ float red[8];
  int w = tid >> 6, l = tid & 63;
  if (l == 0) { red[w] = s; red[4 + w] = q; }
  __syncthreads();
  if (tid == 0) {
    s = red[0] + red[1] + red[2] + red[3];
    q = red[4] + red[5] + red[6] + red[7];
    float m = s * invN, var = q * invN - m * m;
    stats[b * 2] = m; stats[b * 2 + 1] = rsqrtf(var + 1e-5f);
  }
}

// LN apply from bf16 src -> bf16 out (LN1 path)
__global__ __launch_bounds__(256) void k_ln_apply_b(
    const unsigned short* __restrict__ src, const float* __restrict__ stats,
    const float* __restrict__ g, const float* __restrict__ bt,
    unsigned short* __restrict__ outb, int SU) {
  int b = blockIdx.y;
  int idx = (blockIdx.x * 256 + threadIdx.x) * 4;
  float m = stats[b * 2], r = stats[b * 2 + 1];
  u16x4 v4 = *(const u16x4*)(src + (size_t)b * SU + idx);
  float4 gg = *(const float4*)(g + idx);
  float4 bb = *(const float4*)(bt + idx);
  u16x4 ob;
  ob.x = f2bf((bf2f(v4.x) - m) * r * gg.x + bb.x);
  ob.y = f2bf((bf2f(v4.y) - m) * r * gg.y + bb.y);
  ob.z = f2bf((bf2f(v4.z) - m) * r * gg.z + bb.z);
  ob.w = f2bf((bf2f(v4.w) - m) * r * gg.w + bb.w);
  *(u16x4*)(outb + (size_t)b * SU + idx) = ob;
}

// LN apply from stride-2048 f32 rows (FF2 reduce output) -> d_out
__global__ __launch_bounds__(256) void k_ln_apply2(
    const float* __restrict__ src, const float* __restrict__ stats,
    const float* __restrict__ g, const float* __restrict__ bt,
    float* __restrict__ outf) {
  int b = blockIdx.y;
  int row = blockIdx.x;
  int grow = b * 2048 + row;
  int c = threadIdx.x * 4;
  float m = stats[b * 2], r = stats[b * 2 + 1];
  float4 v = *(const float4*)(src + (size_t)grow * 2048 + c);
  float4 gg = *(const float4*)(g + (size_t)row * 1024 + c);
  float4 bb = *(const float4*)(bt + (size_t)row * 1024 + c);
  float4 o;
  o.x = (v.x - m) * r * gg.x + bb.x;
  o.y = (v.y - m) * r * gg.y + bb.y;
  o.z = (v.z - m) * r * gg.z + bb.z;
  o.w = (v.w - m) * r * gg.w + bb.w;
  *(float4*)(outf + (size_t)grow * 1024 + c) = o;
}

extern "C" void kernel_launch(void* const* d_in, const int* in_sizes, int n_in,
                              void* d_out, int out_size, void* d_ws, size_t ws_size,
                              hipStream_t stream) {
  (void)in_sizes; (void)n_in; (void)out_size; (void)ws_size;
  const int S = 2048, H = 16;
  const float* x   = (const float*)d_in[0];
  const float* wq  = (const float*)d_in[1];
  const float* bq  = (const float*)d_in[2];
  const float* wk  = (const float*)d_in[3];
  const float* bk  = (const float*)d_in[4];
  const float* wv  = (const float*)d_in[5];
  const float* bv  = (const float*)d_in[6];
  const float* wf1 = (const float*)d_in[7];
  const float* bf1 = (const float*)d_in[8];
  const float* wf2 = (const float*)d_in[9];
  const float* bf2 = (const float*)d_in[10];
  const float* lng = (const float*)d_in[11];
  const float* lnb = (const float*)d_in[12];
  const float* ffg = (const float*)d_in[13];
  const float* ffb = (const float*)d_in[14];

  char* ws = (char*)d_ws;
  unsigned short* wqkvT = (unsigned short*)(ws);              // 3072x1024 bf16 (dead after QKV)
  unsigned short* wf1T  = (unsigned short*)(ws + 6291456);    // 4096x1024 bf16 (dead after FF1)
  unsigned short* wf2T  = (unsigned short*)(ws + 14680064);   // 1024x4096 bf16
  unsigned short* xb    = (unsigned short*)(ws + 23068672);   // 4096x1024 bf16 (dead after QKV)
  unsigned short* qb    = (unsigned short*)(ws + 31457280);   // 4096x1024 bf16 Q (dead after attn)
  unsigned short* kbuf  = (unsigned short*)(ws + 39845888);   // 4096x1024 bf16 K (dead after attn)
  unsigned short* vt    = (unsigned short*)(ws + 56623104);   // 32x64x2048 bf16 V^T sigma (dead after attn)
  unsigned short* h1b   = (unsigned short*)(ws + 65011712);   // 4096x1024 bf16 (LN1 out)
  unsigned short* hpreb = (unsigned short*)(ws + 73400320);   // 4096x1024 bf16 (attn out, dead after LN1)
  unsigned short* ff2s  = (unsigned short*)(ws + 73400320);   // FF2 slices: 4096x4096 bf16 (over hpreb)
  unsigned short* f1b   = (unsigned short*)(ws + 23068672);   // 4096x4096 bf16 (over xb+qb+kbuf)
  float* biasqkv        = (float*)(ws + 106954752);           // 3072 f32
  float* part_attn      = (float*)(ws + 106967040);           // 2*256*2 f32
  float* stats1         = (float*)(ws + 106977280);           // 2*2 f32
  float* ffpart2        = (float*)(ws);                       // 4096*2 f32 (over wqkvT, dead)
  float* stats2         = (float*)(ws + 65536);               // 2*2 f32 (over wqkvT, dead)

  // Q path pre-scaled by 0.125 * log2(e) for log2-domain softmax
  const float qscale = 0.125f * 1.44269504f;
  k_f32_to_bf16<<<4096, 256, 0, stream>>>(x, xb, 4096 * 1024 / 4);
  k_transpose_w3<<<dim3(16, 16, 3), 256, 0, stream>>>(wq, wk, wv, wqkvT, qscale);
  k_transpose_w<<<dim3(16, 64), 256, 0, stream>>>(wf1, wf1T, 1024, 4096, 1.0f);
  k_transpose_w<<<dim3(64, 16), 256, 0, stream>>>(wf2, wf2T, 4096, 1024, 1.0f);
  k_concat3<<<12, 256, 0, stream>>>(bq, bk, bv, biasqkv, 1024, qscale);

  // QKV projection: split outputs Q | K | V^T(sigma) (no separate transpose pass)
  k_gemm8<4><<<dim3(192, 1, 1), 512, 0, stream>>>(xb, 1024, wqkvT, 1024, biasqkv,
      nullptr, nullptr, 0, 1024, 12, 0, qb, kbuf, vt);

  // causal flash attention (QBLK=128, 4 waves) + x residual -> bf16 + LN1 partials
  k_attn<<<dim3(32, 16), 256, 0, stream>>>(qb, kbuf, vt, x, hpreb, part_attn, S, H);

  // LN1 -> bf16
  k_ln_stats<<<2, 256, 0, stream>>>(part_attn, 256, stats1, 1.f / (2048.f * 1024.f));
  k_ln_apply_b<<<dim3(2048, 2), 256, 0, stream>>>(hpreb, stats1, lng, lnb, h1b, S * 1024);

  // FF1: (4096x1024) @ (1024x4096), ReLU
  k_gemm8<1><<<dim3(256, 1, 1), 512, 0, stream>>>(h1b, 1024, wf1T, 1024, bf1,
      f1b, nullptr, 4096, 1024, 16, 0, nullptr, nullptr, nullptr);

  // FF2: (4096x4096) @ (4096x1024), split-K=4, bf16 row-interleaved slices
  k_gemm8<3><<<dim3(64, 1, 4), 512, 0, stream>>>(f1b, 4096, wf2T, 4096, nullptr,
      ff2s, nullptr, 4096, 1024, 4, 1024, nullptr, nullptr, nullptr);

  // reduce slices + bias + bf16 residual -> f32 rows (stride 2048), LN2 partials
  k_ff2_reduce<<<4096, 256, 0, stream>>>(ff2s, bf2, h1b, ffpart2);

  // LN2 -> d_out (fp32)
  k_ln_stats<<<2, 256, 0, stream>>>(ffpart2, 2048, stats2, 1.f / (2048.f * 1024.f));
  k_ln_apply2<<<dim3(2048, 2), 256, 0, stream>>>((float*)ff2s, stats2, ffg, ffb, (float*)d_out);
}

// Round 16
// 213.476 us; speedup vs baseline: 1.0006x; 1.0006x over previous
//
#include <hip/hip_runtime.h>
#include <hip/hip_bf16.h>

typedef short s16x8 __attribute__((ext_vector_type(8)));
typedef float f32x4 __attribute__((ext_vector_type(4)));
typedef float f32x16 __attribute__((ext_vector_type(16)));
typedef unsigned short u16x4 __attribute__((ext_vector_type(4)));
typedef unsigned u32x4 __attribute__((ext_vector_type(4)));

#define DEV static __device__ __forceinline__

DEV unsigned short f2bf(float f) {  // native cast -> compiler packs pairs into v_cvt_pk_bf16_f32
  __hip_bfloat16 h = __float2bfloat16(f);
  return *reinterpret_cast<unsigned short*>(&h);
}
DEV float bf2f(unsigned short u) {
  union { unsigned u; float f; } v; v.u = (unsigned)u << 16; return v.f;
}

#define GLDS16(src, dst) \
  __builtin_amdgcn_global_load_lds((const __attribute__((address_space(1))) void*)(src), \
                                   (__attribute__((address_space(3))) void*)(dst), 16, 0, 0)

#define MFMA(a, b, c) __builtin_amdgcn_mfma_f32_16x16x32_bf16((a), (b), (c), 0, 0, 0)
#define MFMA32(a, b, c) __builtin_amdgcn_mfma_f32_32x32x16_bf16((a), (b), (c), 0, 0, 0)

// ---------------- elementwise fp32 -> bf16 ----------------
__global__ __launch_bounds__(256) void k_f32_to_bf16(const float* __restrict__ in,
                                                     unsigned short* __restrict__ out, int n4) {
  int i = blockIdx.x * 256 + threadIdx.x;
  if (i >= n4) return;
  float4 v = ((const float4*)in)[i];
  u16x4 o; o.x = f2bf(v.x); o.y = f2bf(v.y); o.z = f2bf(v.z); o.w = f2bf(v.w);
  ((u16x4*)out)[i] = o;
}

// ---------------- weight transpose+convert: (K,N) f32 -> (N,K) bf16, with scale ----------------
__global__ __launch_bounds__(256) void k_transpose_w(const float* __restrict__ W,
                                                     unsigned short* __restrict__ Wt,
                                                     int K, int N, float scale) {
  __shared__ float t[64][65];
  int k0 = blockIdx.x * 64, n0 = blockIdx.y * 64;
  int tid = threadIdx.x;
#pragma unroll
  for (int i = 0; i < 16; ++i) {
    int idx = tid + i * 256; int r = idx >> 6, c = idx & 63;
    t[r][c] = W[(size_t)(k0 + r) * N + (n0 + c)];
  }
  __syncthreads();
#pragma unroll
  for (int i = 0; i < 16; ++i) {
    int idx = tid + i * 256; int r = idx >> 6, c = idx & 63;
    Wt[(size_t)(n0 + r) * K + (k0 + c)] = f2bf(t[c][r] * scale);
  }
}

// QKV fused variant: z selects {wq, wk, wv}; 1024x1024 each; wq gets scale.
__global__ __launch_bounds__(256) void k_transpose_w3(
    const float* __restrict__ W0, const float* __restrict__ W1,
    const float* __restrict__ W2, unsigned short* __restrict__ Wt, float s0) {
  __shared__ float t[64][65];
  int z = blockIdx.z;
  const float* W = (z == 0) ? W0 : (z == 1) ? W1 : W2;
  float scale = (z == 0) ? s0 : 1.0f;
  unsigned short* dst = Wt + (size_t)z * 1024 * 1024;
  int k0 = blockIdx.x * 64, n0 = blockIdx.y * 64;
  int tid = threadIdx.x;
#pragma unroll
  for (int i = 0; i < 16; ++i) {
    int idx = tid + i * 256; int r = idx >> 6, c = idx & 63;
    t[r][c] = W[(size_t)(k0 + r) * 1024 + (n0 + c)];
  }
  __syncthreads();
#pragma unroll
  for (int i = 0; i < 16; ++i) {
    int idx = tid + i * 256; int r = idx >> 6, c = idx & 63;
    dst[(size_t)(n0 + r) * 1024 + (k0 + c)] = f2bf(t[c][r] * scale);
  }
}

// ---------------- concat 3 bias vectors (a gets scale) ----------------
__global__ void k_concat3(const float* __restrict__ a, const float* __restrict__ b,
                          const float* __restrict__ c, float* __restrict__ out, int n, float sa) {
  int i = blockIdx.x * 256 + threadIdx.x;
  if (i >= 3 * n) return;
  int j = (i < n) ? i : (i < 2 * n ? i - n : i - 2 * n);
  out[i] = (i < n) ? a[j] * sa : (i < 2 * n ? b[j] : c[j]);
}

// ---------------- 256x256 4-phase pipelined GEMM (round-14 proven best) ----------------
// BK=64, two k-half granules, 2 LDS tile-buffers, counted vmcnt(4), setprio
// clusters, XOR-swizzled LDS (both-sides), XCD block swizzle. k1-half fragment
// ds_reads prefetched BEFORE the mid barrier (resident since tile entry).
// MODE 0: bias->bf16. MODE 1: bias+relu->bf16. MODE 3: raw bf16 partial at
// Cb + z*zstride. MODE 4: QKV split: nt<4 -> Cq, nt<8 -> Ck, else V scattered
// transposed into Cv[bh][d][sigma(s)] (sigma = swap bits 2<->3 of s%16).
template <int MODE>
__global__ __launch_bounds__(512, 2) void k_gemm8(
    const unsigned short* __restrict__ A, int lda,
    const unsigned short* __restrict__ Bt, int ldb,
    const float* __restrict__ bias,
    unsigned short* __restrict__ Cb, float* __restrict__ Cf, int ldc,
    int K, int nnt, size_t zstride,
    unsigned short* __restrict__ Cq, unsigned short* __restrict__ Ck,
    unsigned short* __restrict__ Cv) {
  __shared__ __align__(16) unsigned short As[2 * 2 * 8192];  // [buf][kh][256][32]
  __shared__ __align__(16) unsigned short Bs[2 * 2 * 8192];
  int nwg = gridDim.x;
  int bid = blockIdx.x;
  int cpx = nwg >> 3;
  int swz = (bid & 7) * cpx + (bid >> 3);
  int mt = swz / nnt, nt = swz % nnt;
  int m0 = mt * 256, n0 = nt * 256;
  int tid = threadIdx.x, w = tid >> 6, l = tid & 63;
  int wm = (w >> 2) * 128, wn = (w & 3) * 64;
  int kb = blockIdx.z * K;

  int sr = tid >> 2;
  int gsrc = (tid & 3) ^ ((sr >> 1) & 3);
  const unsigned short* Ag0 = A + (size_t)(m0 + sr) * lda + kb + gsrc * 8;
  const unsigned short* Ag1 = Ag0 + (size_t)128 * lda;
  const unsigned short* Bg0 = Bt + (size_t)(n0 + sr) * ldb + kb + gsrc * 8;
  const unsigned short* Bg1 = Bg0 + (size_t)128 * ldb;

#define STG_A(t, kh) do { int _c = (t) * 64 + (kh) * 32; int _d = ((((t) & 1) * 2 + (kh)) * 8192); \
    GLDS16(Ag0 + _c, &As[_d + tid * 8]); GLDS16(Ag1 + _c, &As[_d + 4096 + tid * 8]); } while (0)
#define STG_B(t, kh) do { int _c = (t) * 64 + (kh) * 32; int _d = ((((t) & 1) * 2 + (kh)) * 8192); \
    GLDS16(Bg0 + _c, &Bs[_d + tid * 8]); GLDS16(Bg1 + _c, &Bs[_d + 4096 + tid * 8]); } while (0)

  int lswz = (l >> 1) & 3;
  int acol = ((l >> 4) ^ lswz) * 8;
  const unsigned short* Afr = &As[(wm + (l & 15)) * 32 + acol];
  const unsigned short* Bfr = &Bs[(wn + (l & 15)) * 32 + acol];

  f32x4 acc[8][4] = {};
  int nkt = K >> 6;

  STG_A(0, 0); STG_B(0, 0); STG_A(0, 1); STG_B(0, 1); STG_A(1, 0); STG_B(1, 0);
  asm volatile("s_waitcnt vmcnt(4)" ::: "memory");
  __builtin_amdgcn_s_barrier();
  __builtin_amdgcn_sched_barrier(0);

  for (int t = 0; t < nkt; ++t) {
    int cur = t & 1, rem = nkt - t;
    const unsigned short* ab = Afr + cur * 16384;
    const unsigned short* bb = Bfr + cur * 16384;
    s16x8 af[4], bf[4], afn[4], bfn[4];
    // ---- p1: (mhalf0, k0) ----
    if (t + 1 < nkt) STG_A(t + 1, 1);
#pragma unroll
    for (int nr = 0; nr < 4; ++nr) bf[nr] = *(const s16x8*)(bb + nr * 512);
#pragma unroll
    for (int mr = 0; mr < 4; ++mr) af[mr] = *(const s16x8*)(ab + mr * 512);
    __builtin_amdgcn_s_setprio(1);
#pragma unroll
    for (int mr = 0; mr < 4; ++mr)
#pragma unroll
      for (int nr = 0; nr < 4; ++nr)
        acc[mr][nr] = MFMA(af[mr], bf[nr], acc[mr][nr]);
    __builtin_amdgcn_s_setprio(0);
    // ---- p2: (mhalf1, k0) ----
    if (t + 1 < nkt) STG_B(t + 1, 1);
#pragma unroll
    for (int mr = 0; mr < 4; ++mr) af[mr] = *(const s16x8*)(ab + 2048 + mr * 512);
    __builtin_amdgcn_s_setprio(1);
#pragma unroll
    for (int mr = 0; mr < 4; ++mr)
#pragma unroll
      for (int nr = 0; nr < 4; ++nr)
        acc[mr + 4][nr] = MFMA(af[mr], bf[nr], acc[mr + 4][nr]);
    __builtin_amdgcn_s_setprio(0);
    // ---- prefetch k1(t) fragments (resident since tile entry) ----
#pragma unroll
    for (int nr = 0; nr < 4; ++nr) bfn[nr] = *(const s16x8*)(bb + 8192 + nr * 512);
#pragma unroll
    for (int mr = 0; mr < 4; ++mr) afn[mr] = *(const s16x8*)(ab + 8192 + mr * 512);
#pragma unroll
    for (int mr = 0; mr < 4; ++mr) af[mr] = *(const s16x8*)(ab + 8192 + 2048 + mr * 512);
    if (rem >= 2) { asm volatile("s_waitcnt vmcnt(4)" ::: "memory"); }
    else          { asm volatile("s_waitcnt vmcnt(0)" ::: "memory"); }
    __builtin_amdgcn_s_barrier();
    // ---- p3: (mhalf0, k1) ----
    if (t + 2 < nkt) STG_A(t + 2, 0);
    __builtin_amdgcn_s_setprio(1);
#pragma unroll
    for (int mr = 0; mr < 4; ++mr)
#pragma unroll
      for (int nr = 0; nr < 4; ++nr)
        acc[mr][nr] = MFMA(afn[mr], bfn[nr], acc[mr][nr]);
    __builtin_amdgcn_s_setprio(0);
    // ---- p4: (mhalf1, k1) ----
    if (t + 2 < nkt) STG_B(t + 2, 0);
    __builtin_amdgcn_s_setprio(1);
#pragma unroll
    for (int mr = 0; mr < 4; ++mr)
#pragma unroll
      for (int nr = 0; nr < 4; ++nr)
        acc[mr + 4][nr] = MFMA(af[mr], bfn[nr], acc[mr + 4][nr]);
    __builtin_amdgcn_s_setprio(0);
    if (rem >= 3) { asm volatile("s_waitcnt vmcnt(4)" ::: "memory"); }
    else          { asm volatile("s_waitcnt vmcnt(0)" ::: "memory"); }
    __builtin_amdgcn_s_barrier();
    __builtin_amdgcn_sched_barrier(0);
  }
#undef STG_A
#undef STG_B

  if (MODE == 4) {
    if (nt < 8) {
      unsigned short* dst = (nt < 4) ? Cq : Ck;
      int cb = (nt < 4) ? 0 : 1024;
#pragma unroll
      for (int mr = 0; mr < 8; ++mr) {
        int rb = m0 + wm + mr * 16 + (l >> 4) * 4;
#pragma unroll
        for (int nr = 0; nr < 4; ++nr) {
          int col = n0 + wn + nr * 16 + (l & 15);
          float bv = bias[col];
#pragma unroll
          for (int j = 0; j < 4; ++j)
            dst[(size_t)(rb + j) * 1024 + (col - cb)] = f2bf(acc[mr][nr][j] + bv);
        }
      }
    } else {  // V: scatter transposed into Cv[bh][d][sigma(s)], sigma = swap bits 2<->3
#pragma unroll
      for (int mr = 0; mr < 8; ++mr) {
        int rb = m0 + wm + mr * 16 + (l >> 4) * 4;
        int b2 = rb >> 11, s2 = rb & 2047;
        int s2p = (s2 & ~12) | ((s2 & 4) << 1) | ((s2 & 8) >> 1);
#pragma unroll
        for (int nr = 0; nr < 4; ++nr) {
          int col2 = n0 - 2048 + wn + nr * 16 + (l & 15);
          float bv = bias[col2 + 2048];
          u16x4 pk;
#pragma unroll
          for (int j = 0; j < 4; ++j) ((unsigned short*)&pk)[j] = f2bf(acc[mr][nr][j] + bv);
          *(u16x4*)(Cv + ((size_t)((b2 * 16 + (col2 >> 6)) * 64 + (col2 & 63))) * 2048 + s2p) = pk;
        }
      }
    }
    return;
  }
  unsigned short* Cbz = (MODE == 3) ? (Cb + zstride * blockIdx.z) : Cb;
#pragma unroll
  for (int mr = 0; mr < 8; ++mr) {
    int rb = m0 + wm + mr * 16 + (l >> 4) * 4;
#pragma unroll
    for (int nr = 0; nr < 4; ++nr) {
      int col = n0 + wn + nr * 16 + (l & 15);
      float bv = (MODE == 3) ? 0.f : bias[col];
#pragma unroll
      for (int j = 0; j < 4; ++j) {
        float v = acc[mr][nr][j] + bv;
        size_t off = (size_t)(rb + j) * ldc + col;
        if (MODE == 1) v = fmaxf(v, 0.f);
        Cbz[off] = f2bf(v);
      }
    }
  }
}

// ---------------- FF2 split-K=4 reduce (row-interleaved bf16 slices) ----------------
__global__ __launch_bounds__(256) void k_ff2_reduce(
    unsigned short* __restrict__ slices, const float* __restrict__ bias,
    const unsigned short* __restrict__ resid, float* __restrict__ partials) {
  __shared__ float red[8];
  int i = blockIdx.x;
  size_t rb = (size_t)i * 4096;
  int c = threadIdx.x * 4;
  u16x4 a0 = *(const u16x4*)(slices + rb + c);
  u16x4 a1 = *(const u16x4*)(slices + rb + 1024 + c);
  u16x4 a2 = *(const u16x4*)(slices + rb + 2048 + c);
  u16x4 a3 = *(const u16x4*)(slices + rb + 3072 + c);
  float4 bv = *(const float4*)(bias + c);
  u16x4 rv = *(const u16x4*)(resid + (size_t)i * 1024 + c);
  float4 o;
  o.x = bf2f(a0.x) + bf2f(a1.x) + bf2f(a2.x) + bf2f(a3.x) + bv.x + bf2f(rv.x);
  o.y = bf2f(a0.y) + bf2f(a1.y) + bf2f(a2.y) + bf2f(a3.y) + bv.y + bf2f(rv.y);
  o.z = bf2f(a0.z) + bf2f(a1.z) + bf2f(a2.z) + bf2f(a3.z) + bv.z + bf2f(rv.z);
  o.w = bf2f(a0.w) + bf2f(a1.w) + bf2f(a2.w) + bf2f(a3.w) + bv.w + bf2f(rv.w);
  __syncthreads();
  *(float4*)((float*)slices + (size_t)i * 2048 + c) = o;
  float bsum = o.x + o.y + o.z + o.w;
  float bsq = o.x * o.x + o.y * o.y + o.z * o.z + o.w * o.w;
  int wv = threadIdx.x >> 6, lv = threadIdx.x & 63;
#pragma unroll
  for (int mk = 1; mk < 64; mk <<= 1) { bsum += __shfl_xor(bsum, mk); bsq += __shfl_xor(bsq, mk); }
  if (lv == 0) { red[wv] = bsum; red[4 + wv] = bsq; }
  __syncthreads();
  if (threadIdx.x == 0) {
    partials[i * 2] = red[0] + red[1] + red[2] + red[3];
    partials[i * 2 + 1] = red[4] + red[5] + red[6] + red[7];
  }
}

// ---------------- causal flash attention, QBLK=128 (4 waves), 32x32 MFMA ----------------
// (round-14 proven; residual now read from bf16 xb, halving that HBM stream.)
__global__ __launch_bounds__(256, 2) void k_attn(
    const unsigned short* __restrict__ Qg, const unsigned short* __restrict__ Kg,
    const unsigned short* __restrict__ Vt,
    const unsigned short* __restrict__ xbg, unsigned short* __restrict__ hpre,
    float* __restrict__ partials, int S, int H) {
  __shared__ __align__(16) unsigned short Ks[2][4096];
  __shared__ __align__(16) unsigned short Vs[2][4096];
  __shared__ float ascr[4][32];
  __shared__ float red[8];
  int bh = blockIdx.x, b = bh >> 4, h = bh & 15;
  int y = (int)blockIdx.y;
  int qt = (y < 8) ? (15 - y) : (y - 8);
  int tid = threadIdx.x, w = tid >> 6, l = tid & 63;
  int lo = l & 31, hi5 = l >> 5;
  const int U = H * 64;
  const unsigned short* Qb = Qg + (size_t)(b * S) * 1024 + h * 64;
  const unsigned short* Kb = Kg + (size_t)(b * S) * 1024 + h * 64;
  const unsigned short* Vb = Vt + (size_t)bh * 64 * S;
  int tl = 2 * qt + 1;

  int sg_r[2], sg_c[2];
#pragma unroll
  for (int it = 0; it < 2; ++it) {
    int g = it * 256 + tid;
    sg_r[it] = g >> 3;
    sg_c[it] = ((g & 7) ^ ((g >> 3) & 7)) * 8;
  }
#define STG_K(kt) do { int _kn = (kt) * 64, _bf = (kt) & 1; \
    _Pragma("unroll") for (int it = 0; it < 2; ++it) \
      GLDS16(Kb + (size_t)(_kn + sg_r[it]) * 1024 + sg_c[it], &Ks[_bf][(it * 256 + tid) * 8]); } while (0)
#define STG_V(kt) do { int _kn = (kt) * 64, _bf = (kt) & 1; \
    _Pragma("unroll") for (int it = 0; it < 2; ++it) \
      GLDS16(Vb + (size_t)sg_r[it] * S + _kn + sg_c[it], &Vs[_bf][(it * 256 + tid) * 8]); } while (0)

  int qrow = qt * 128 + w * 32 + lo;
  s16x8 qf[4];
#pragma unroll
  for (int s = 0; s < 4; ++s)
    qf[s] = *(const s16x8*)(Qb + (size_t)qrow * 1024 + s * 16 + hi5 * 8);

  int krow[16];
#pragma unroll
  for (int r = 0; r < 16; ++r) krow[r] = (r & 3) + 8 * (r >> 2) + 4 * hi5;
  int wq = w * 32 + lo;

  f32x16 o0 = {}, o1 = {};
  float m = -1e30f, lsum = 0.f;
  f32x16 scA0, scA1, scB0, scB1;

#define MBASE(T) (((T) >= 2 * qt) ? ((T) * 64 - qt * 128) : -1)

#define QK_T(S0, S1, T) do { \
    S0 = (f32x16)(0.0f); S1 = (f32x16)(0.0f); \
    const unsigned short* _kp = &Ks[(T) & 1][0]; \
    __builtin_amdgcn_s_setprio(1); \
    _Pragma("unroll") for (int s = 0; s < 4; ++s) { \
      int gc = ((2 * s + hi5) ^ (lo & 7)) * 8; \
      s16x8 kf0 = *(const s16x8*)&_kp[lo * 64 + gc]; \
      s16x8 kf1 = *(const s16x8*)&_kp[(32 + lo) * 64 + gc]; \
      S0 = MFMA32(kf0, qf[s], S0); \
      S1 = MFMA32(kf1, qf[s], S1); } \
    __builtin_amdgcn_s_setprio(0); } while (0)

#define SMPV(S0, S1, T, MB) do { \
    if ((MB) >= 0) { \
      _Pragma("unroll") for (int r = 0; r < 16; ++r) { \
        if (krow[r] + (MB) > wq) S0[r] = -1e30f; \
        if (krow[r] + 32 + (MB) > wq) S1[r] = -1e30f; } } \
    float mx = S0[0]; \
    _Pragma("unroll") for (int r = 1; r < 16; ++r) mx = fmaxf(mx, S0[r]); \
    _Pragma("unroll") for (int r = 0; r < 16; ++r) mx = fmaxf(mx, S1[r]); \
    mx = fmaxf(mx, __shfl_xor(mx, 32)); \
    if (__ballot(mx > m + 11.5415603f)) { \
      float mnew = fmaxf(m, mx); \
      float alpha = __builtin_amdgcn_exp2f(m - mnew); \
      m = mnew; lsum *= alpha; \
      if (l < 32) ascr[w][lo] = alpha; \
      _Pragma("unroll") for (int r = 0; r < 16; ++r) { \
        float aj = ascr[w][krow[r]]; o0[r] *= aj; o1[r] *= aj; } } \
    float rs = 0.f; unsigned wk0[8], wk1[8]; \
    _Pragma("unroll") for (int j = 0; j < 8; ++j) { \
      float p0 = __builtin_amdgcn_exp2f(S0[2 * j] - m); \
      float p1 = __builtin_amdgcn_exp2f(S0[2 * j + 1] - m); \
      rs += p0 + p1; wk0[j] = (unsigned)f2bf(p0) | ((unsigned)f2bf(p1) << 16); \
      float p2 = __builtin_amdgcn_exp2f(S1[2 * j] - m); \
      float p3 = __builtin_amdgcn_exp2f(S1[2 * j + 1] - m); \
      rs += p2 + p3; wk1[j] = (unsigned)f2bf(p2) | ((unsigned)f2bf(p3) << 16); } \
    rs += __shfl_xor(rs, 32); lsum += rs; \
    __builtin_amdgcn_s_setprio(1); \
    _Pragma("unroll") for (int s = 0; s < 4; ++s) { \
      u32x4 paw; \
      if (s == 0)      { paw.x = wk0[0]; paw.y = wk0[1]; paw.z = wk0[2]; paw.w = wk0[3]; } \
      else if (s == 1) { paw.x = wk0[4]; paw.y = wk0[5]; paw.z = wk0[6]; paw.w = wk0[7]; } \
      else if (s == 2) { paw.x = wk1[0]; paw.y = wk1[1]; paw.z = wk1[2]; paw.w = wk1[3]; } \
      else             { paw.x = wk1[4]; paw.y = wk1[5]; paw.z = wk1[6]; paw.w = wk1[7]; } \
      s16x8 pa = *(s16x8*)&paw; \
      int gc = ((2 * s + hi5) ^ (lo & 7)) * 8; \
      s16x8 vf0 = *(const s16x8*)&Vs[(T) & 1][lo * 64 + gc]; \
      s16x8 vf1 = *(const s16x8*)&Vs[(T) & 1][(32 + lo) * 64 + gc]; \
      o0 = MFMA32(pa, vf0, o0); \
      o1 = MFMA32(pa, vf1, o1); } \
    __builtin_amdgcn_s_setprio(0); \
  } while (0)

#define BODY(O0, O1, I0, I1, T) do { \
    asm volatile("s_waitcnt vmcnt(2)" ::: "memory"); \
    __builtin_amdgcn_s_barrier(); \
    __builtin_amdgcn_sched_barrier(0); \
    if ((T) + 1 <= tl) STG_K((T) + 1); \
    QK_T(O0, O1, (T)); \
    SMPV(I0, I1, (T) - 1, MBASE((T) - 1)); \
    asm volatile("s_waitcnt lgkmcnt(0)" ::: "memory"); \
    __builtin_amdgcn_sched_barrier(0); \
    __builtin_amdgcn_s_barrier(); \
    __builtin_amdgcn_sched_barrier(0); \
    if ((T) + 1 <= tl) STG_V((T) + 1); \
  } while (0)

  STG_K(0); STG_V(0); STG_K(1); STG_V(1);
  asm volatile("s_waitcnt vmcnt(4)" ::: "memory");
  __builtin_amdgcn_s_barrier();
  __builtin_amdgcn_sched_barrier(0);
  QK_T(scA0, scA1, 0);
  asm volatile("s_waitcnt lgkmcnt(0)" ::: "memory");
  __builtin_amdgcn_sched_barrier(0);

  int t = 1;
  for (; t + 1 <= tl; t += 2) {
    BODY(scB0, scB1, scA0, scA1, t);
    BODY(scA0, scA1, scB0, scB1, t + 1);
  }
  if (t <= tl) {
    BODY(scB0, scB1, scA0, scA1, t);
    asm volatile("s_waitcnt vmcnt(0)" ::: "memory");
    __builtin_amdgcn_sched_barrier(0);
    SMPV(scB0, scB1, tl, MBASE(tl));
  } else {
    asm volatile("s_waitcnt vmcnt(0)" ::: "memory");
    __builtin_amdgcn_sched_barrier(0);
    SMPV(scA0, scA1, tl, MBASE(tl));
  }

  // ---- epilogue: O/l + bf16 x residual -> bf16, LN partials ----
  if (l < 32) ascr[w][lo] = 1.f / lsum;
  float bsum = 0.f, bsq = 0.f;
  unsigned short* hb = hpre + (size_t)(b * S) * U + h * 64;
  const unsigned short* xb = xbg + (size_t)(b * S) * U + h * 64;
#pragma unroll
  for (int r = 0; r < 16; ++r) {
    float inv = ascr[w][krow[r]];
    int srow = qt * 128 + w * 32 + krow[r];
    size_t base = (size_t)srow * U + lo;
    float v0 = o0[r] * inv + bf2f(xb[base]);
    float v1 = o1[r] * inv + bf2f(xb[base + 32]);
    hb[base] = f2bf(v0);
    hb[base + 32] = f2bf(v1);
    bsum += v0 + v1; bsq += v0 * v0 + v1 * v1;
  }
#pragma unroll
  for (int mk = 1; mk < 64; mk <<= 1) { bsum += __shfl_xor(bsum, mk); bsq += __shfl_xor(bsq, mk); }
  if (l == 0) { red[w * 2] = bsum; red[w * 2 + 1] = bsq; }
  __syncthreads();
  if (tid == 0) {
    int pi = b * (H * 16) + h * 16 + qt;
    partials[pi * 2] = red[0] + red[2] + red[4] + red[6];
    partials[pi * 2 + 1] = red[1] + red[3] + red[5] + red[7];
  }
#undef STG_K
#undef STG_V
#undef QK_T
#undef SMPV
#undef BODY
#undef MBASE
}

// ---------------- LN over (S,U) per batch ----------------
__global__ __launch_bounds__(256) void k_ln_stats(const float* __restrict__ partials, int nper,
                                                  float* __restrict__ stats, float invN) {
  int b = blockIdx.x, tid = threadIdx.x;
  float s = 0.f, q = 0.f;
  for (int i = tid; i < nper; i += 256) { s += partials[(b * nper + i) * 2]; q += partials[(b * nper + i) * 2 + 1]; }
#pragma unroll
  for (int mk = 1; mk < 64; mk <<= 1) { s += __shfl_xor(s, mk); q += __shfl_xor(q, mk); }
  __shared__ float red[8];
  int w = tid >> 6, l = tid & 63;
  if (l == 0) { red[w] = s; red[4 + w] = q; }
  __syncthreads();
  if (tid == 0) {
    s = red[0] + red[1] + red[2] + red[3];
    q = red[4] + red[5] + red[6] + red[7];
    float m = s * invN, var = q * invN - m * m;
    stats[b * 2] = m; stats[b * 2 + 1] = rsqrtf(var + 1e-5f);
  }
}

// LN apply from bf16 src -> bf16 out (LN1 path)
__global__ __launch_bounds__(256) void k_ln_apply_b(
    const unsigned short* __restrict__ src, const float* __restrict__ stats,
    const float* __restrict__ g, const float* __restrict__ bt,
    unsigned short* __restrict__ outb, int SU) {
  int b = blockIdx.y;
  int idx = (blockIdx.x * 256 + threadIdx.x) * 4;
  float m = stats[b * 2], r = stats[b * 2 + 1];
  u16x4 v4 = *(const u16x4*)(src + (size_t)b * SU + idx);
  float4 gg = *(const float4*)(g + idx);
  float4 bb = *(const float4*)(bt + idx);
  u16x4 ob;
  ob.x = f2bf((bf2f(v4.x) - m) * r * gg.x + bb.x);
  ob.y = f2bf((bf2f(v4.y) - m) * r * gg.y + bb.y);
  ob.z = f2bf((bf2f(v4.z) - m) * r * gg.z + bb.z);
  ob.w = f2bf((bf2f(v4.w) - m) * r * gg.w + bb.w);
  *(u16x4*)(outb + (size_t)b * SU + idx) = ob;
}

// LN apply from stride-2048 f32 rows (FF2 reduce output) -> d_out
__global__ __launch_bounds__(256) void k_ln_apply2(
    const float* __restrict__ src, const float* __restrict__ stats,
    const float* __restrict__ g, const float* __restrict__ bt,
    float* __restrict__ outf) {
  int b = blockIdx.y;
  int row = blockIdx.x;
  int grow = b * 2048 + row;
  int c = threadIdx.x * 4;
  float m = stats[b * 2], r = stats[b * 2 + 1];
  float4 v = *(const float4*)(src + (size_t)grow * 2048 + c);
  float4 gg = *(const float4*)(g + (size_t)row * 1024 + c);
  float4 bb = *(const float4*)(bt + (size_t)row * 1024 + c);
  float4 o;
  o.x = (v.x - m) * r * gg.x + bb.x;
  o.y = (v.y - m) * r * gg.y + bb.y;
  o.z = (v.z - m) * r * gg.z + bb.z;
  o.w = (v.w - m) * r * gg.w + bb.w;
  *(float4*)(outf + (size_t)grow * 1024 + c) = o;
}

extern "C" void kernel_launch(void* const* d_in, const int* in_sizes, int n_in,
                              void* d_out, int out_size, void* d_ws, size_t ws_size,
                              hipStream_t stream) {
  (void)in_sizes; (void)n_in; (void)out_size; (void)ws_size;
  const int S = 2048, H = 16;
  const float* x   = (const float*)d_in[0];
  const float* wq  = (const float*)d_in[1];
  const float* bq  = (const float*)d_in[2];
  const float* wk  = (const float*)d_in[3];
  const float* bk  = (const float*)d_in[4];
  const float* wv  = (const float*)d_in[5];
  const float* bv  = (const float*)d_in[6];
  const float* wf1 = (const float*)d_in[7];
  const float* bf1 = (const float*)d_in[8];
  const float* wf2 = (const float*)d_in[9];
  const float* bf2 = (const float*)d_in[10];
  const float* lng = (const float*)d_in[11];
  const float* lnb = (const float*)d_in[12];
  const float* ffg = (const float*)d_in[13];
  const float* ffb = (const float*)d_in[14];

  char* ws = (char*)d_ws;
  unsigned short* wqkvT = (unsigned short*)(ws);              // 3072x1024 bf16 (dead after QKV)
  unsigned short* wf1T  = (unsigned short*)(ws + 6291456);    // 4096x1024 bf16 (dead after FF1)
  unsigned short* wf2T  = (unsigned short*)(ws + 14680064);   // 1024x4096 bf16
  unsigned short* xb    = (unsigned short*)(ws + 23068672);   // 4096x1024 bf16 (live through attn)
  unsigned short* qb    = (unsigned short*)(ws + 31457280);   // 4096x1024 bf16 Q (dead after attn)
  unsigned short* kbuf  = (unsigned short*)(ws + 39845888);   // 4096x1024 bf16 K (dead after attn)
  unsigned short* vt    = (unsigned short*)(ws + 56623104);   // 32x64x2048 bf16 V^T sigma (dead after attn)
  unsigned short* h1b   = (unsigned short*)(ws + 65011712);   // 4096x1024 bf16 (LN1 out)
  unsigned short* hpreb = (unsigned short*)(ws + 73400320);   // 4096x1024 bf16 (attn out, dead after LN1)
  unsigned short* ff2s  = (unsigned short*)(ws + 73400320);   // FF2 slices: 4096x4096 bf16 (over hpreb)
  unsigned short* f1b   = (unsigned short*)(ws + 23068672);   // 4096x4096 bf16 (over xb+qb+kbuf)
  float* biasqkv        = (float*)(ws + 106954752);           // 3072 f32
  float* part_attn      = (float*)(ws + 106967040);           // 2*256*2 f32
  float* stats1         = (float*)(ws + 106977280);           // 2*2 f32
  float* ffpart2        = (float*)(ws);                       // 4096*2 f32 (over wqkvT, dead)
  float* stats2         = (float*)(ws + 65536);               // 2*2 f32 (over wqkvT, dead)

  // Q path pre-scaled by 0.125 * log2(e) for log2-domain softmax
  const float qscale = 0.125f * 1.44269504f;
  k_f32_to_bf16<<<4096, 256, 0, stream>>>(x, xb, 4096 * 1024 / 4);
  k_transpose_w3<<<dim3(16, 16, 3), 256, 0, stream>>>(wq, wk, wv, wqkvT, qscale);
  k_transpose_w<<<dim3(16, 64), 256, 0, stream>>>(wf1, wf1T, 1024, 4096, 1.0f);
  k_transpose_w<<<dim3(64, 16), 256, 0, stream>>>(wf2, wf2T, 4096, 1024, 1.0f);
  k_concat3<<<12, 256, 0, stream>>>(bq, bk, bv, biasqkv, 1024, qscale);

  // QKV projection: split outputs Q | K | V^T(sigma) (no separate transpose pass)
  k_gemm8<4><<<dim3(192, 1, 1), 512, 0, stream>>>(xb, 1024, wqkvT, 1024, biasqkv,
      nullptr, nullptr, 0, 1024, 12, 0, qb, kbuf, vt);

  // causal flash attention (QBLK=128, 4 waves) + bf16 x residual -> bf16 + LN1 partials
  k_attn<<<dim3(32, 16), 256, 0, stream>>>(qb, kbuf, vt, xb, hpreb, part_attn, S, H);

  // LN1 -> bf16
  k_ln_stats<<<2, 256, 0, stream>>>(part_attn, 256, stats1, 1.f / (2048.f * 1024.f));
  k_ln_apply_b<<<dim3(2048, 2), 256, 0, stream>>>(hpreb, stats1, lng, lnb, h1b, S * 1024);

  // FF1: (4096x1024) @ (1024x4096), ReLU
  k_gemm8<1><<<dim3(256, 1, 1), 512, 0, stream>>>(h1b, 1024, wf1T, 1024, bf1,
      f1b, nullptr, 4096, 1024, 16, 0, nullptr, nullptr, nullptr);

  // FF2: (4096x4096) @ (4096x1024), split-K=4, bf16 row-interleaved slices
  k_gemm8<3><<<dim3(64, 1, 4), 512, 0, stream>>>(f1b, 4096, wf2T, 4096, nullptr,
      ff2s, nullptr, 4096, 1024, 4, 1024, nullptr, nullptr, nullptr);

  // reduce slices + bias + bf16 residual -> f32 rows (stride 2048), LN2 partials
  k_ff2_reduce<<<4096, 256, 0, stream>>>(ff2s, bf2, h1b, ffpart2);

  // LN2 -> d_out (fp32)
  k_ln_stats<<<2, 256, 0, stream>>>(ffpart2, 2048, stats2, 1.f / (2048.f * 1024.f));
  k_ln_apply2<<<dim3(2048, 2), 256, 0, stream>>>((float*)ff2s, stats2, ffg, ffb, (float*)d_out);
}

// Round 17
// 212.708 us; speedup vs baseline: 1.0042x; 1.0036x over previous
//
#include <hip/hip_runtime.h>
#include <hip/hip_bf16.h>

typedef short s16x8 __attribute__((ext_vector_type(8)));
typedef float f32x4 __attribute__((ext_vector_type(4)));
typedef float f32x16 __attribute__((ext_vector_type(16)));
typedef unsigned short u16x4 __attribute__((ext_vector_type(4)));
typedef unsigned u32x4 __attribute__((ext_vector_type(4)));

#define DEV static __device__ __forceinline__

DEV unsigned short f2bf(float f) {  // native cast -> compiler packs pairs into v_cvt_pk_bf16_f32
  __hip_bfloat16 h = __float2bfloat16(f);
  return *reinterpret_cast<unsigned short*>(&h);
}
DEV float bf2f(unsigned short u) {
  union { unsigned u; float f; } v; v.u = (unsigned)u << 16; return v.f;
}

#define GLDS16(src, dst) \
  __builtin_amdgcn_global_load_lds((const __attribute__((address_space(1))) void*)(src), \
                                   (__attribute__((address_space(3))) void*)(dst), 16, 0, 0)

#define MFMA(a, b, c) __builtin_amdgcn_mfma_f32_16x16x32_bf16((a), (b), (c), 0, 0, 0)
#define MFMA32(a, b, c) __builtin_amdgcn_mfma_f32_32x32x16_bf16((a), (b), (c), 0, 0, 0)

// ---------------- elementwise fp32 -> bf16 ----------------
__global__ __launch_bounds__(256) void k_f32_to_bf16(const float* __restrict__ in,
                                                     unsigned short* __restrict__ out, int n4) {
  int i = blockIdx.x * 256 + threadIdx.x;
  if (i >= n4) return;
  float4 v = ((const float4*)in)[i];
  u16x4 o; o.x = f2bf(v.x); o.y = f2bf(v.y); o.z = f2bf(v.z); o.w = f2bf(v.w);
  ((u16x4*)out)[i] = o;
}

// ---------------- weight transpose+convert: (K,N) f32 -> (N,K) bf16, with scale ----------------
__global__ __launch_bounds__(256) void k_transpose_w(const float* __restrict__ W,
                                                     unsigned short* __restrict__ Wt,
                                                     int K, int N, float scale) {
  __shared__ float t[64][65];
  int k0 = blockIdx.x * 64, n0 = blockIdx.y * 64;
  int tid = threadIdx.x;
#pragma unroll
  for (int i = 0; i < 16; ++i) {
    int idx = tid + i * 256; int r = idx >> 6, c = idx & 63;
    t[r][c] = W[(size_t)(k0 + r) * N + (n0 + c)];
  }
  __syncthreads();
#pragma unroll
  for (int i = 0; i < 16; ++i) {
    int idx = tid + i * 256; int r = idx >> 6, c = idx & 63;
    Wt[(size_t)(n0 + r) * K + (k0 + c)] = f2bf(t[c][r] * scale);
  }
}

// QKV fused variant: z selects {wq, wk, wv}; 1024x1024 each; wq gets scale.
__global__ __launch_bounds__(256) void k_transpose_w3(
    const float* __restrict__ W0, const float* __restrict__ W1,
    const float* __restrict__ W2, unsigned short* __restrict__ Wt, float s0) {
  __shared__ float t[64][65];
  int z = blockIdx.z;
  const float* W = (z == 0) ? W0 : (z == 1) ? W1 : W2;
  float scale = (z == 0) ? s0 : 1.0f;
  unsigned short* dst = Wt + (size_t)z * 1024 * 1024;
  int k0 = blockIdx.x * 64, n0 = blockIdx.y * 64;
  int tid = threadIdx.x;
#pragma unroll
  for (int i = 0; i < 16; ++i) {
    int idx = tid + i * 256; int r = idx >> 6, c = idx & 63;
    t[r][c] = W[(size_t)(k0 + r) * 1024 + (n0 + c)];
  }
  __syncthreads();
#pragma unroll
  for (int i = 0; i < 16; ++i) {
    int idx = tid + i * 256; int r = idx >> 6, c = idx & 63;
    dst[(size_t)(n0 + r) * 1024 + (k0 + c)] = f2bf(t[c][r] * scale);
  }
}

// ---------------- concat 3 bias vectors (a gets scale) ----------------
__global__ void k_concat3(const float* __restrict__ a, const float* __restrict__ b,
                          const float* __restrict__ c, float* __restrict__ out, int n, float sa) {
  int i = blockIdx.x * 256 + threadIdx.x;
  if (i >= 3 * n) return;
  int j = (i < n) ? i : (i < 2 * n ? i - n : i - 2 * n);
  out[i] = (i < n) ? a[j] * sa : (i < 2 * n ? b[j] : c[j]);
}

// ---------------- 256x256 4-phase pipelined GEMM (round-14 proven best) ----------------
// BK=64, two k-half granules, 2 LDS tile-buffers, counted vmcnt(4), setprio
// clusters, XOR-swizzled LDS (both-sides), XCD block swizzle. k1-half fragment
// ds_reads prefetched BEFORE the mid barrier (resident since tile entry).
// MODE 0: bias->bf16. MODE 1: bias+relu->bf16. MODE 3: raw bf16 partial at
// Cb + z*zstride. MODE 4: QKV split: nt<4 -> Cq, nt<8 -> Ck, else V scattered
// transposed into Cv[bh][d][sigma(s)] (sigma = swap bits 2<->3 of s%16).
template <int MODE>
__global__ __launch_bounds__(512, 2) void k_gemm8(
    const unsigned short* __restrict__ A, int lda,
    const unsigned short* __restrict__ Bt, int ldb,
    const float* __restrict__ bias,
    unsigned short* __restrict__ Cb, float* __restrict__ Cf, int ldc,
    int K, int nnt, size_t zstride,
    unsigned short* __restrict__ Cq, unsigned short* __restrict__ Ck,
    unsigned short* __restrict__ Cv) {
  __shared__ __align__(16) unsigned short As[2 * 2 * 8192];  // [buf][kh][256][32]
  __shared__ __align__(16) unsigned short Bs[2 * 2 * 8192];
  int nwg = gridDim.x;
  int bid = blockIdx.x;
  int cpx = nwg >> 3;
  int swz = (bid & 7) * cpx + (bid >> 3);
  int mt = swz / nnt, nt = swz % nnt;
  int m0 = mt * 256, n0 = nt * 256;
  int tid = threadIdx.x, w = tid >> 6, l = tid & 63;
  int wm = (w >> 2) * 128, wn = (w & 3) * 64;
  int kb = blockIdx.z * K;

  int sr = tid >> 2;
  int gsrc = (tid & 3) ^ ((sr >> 1) & 3);
  const unsigned short* Ag0 = A + (size_t)(m0 + sr) * lda + kb + gsrc * 8;
  const unsigned short* Ag1 = Ag0 + (size_t)128 * lda;
  const unsigned short* Bg0 = Bt + (size_t)(n0 + sr) * ldb + kb + gsrc * 8;
  const unsigned short* Bg1 = Bg0 + (size_t)128 * ldb;

#define STG_A(t, kh) do { int _c = (t) * 64 + (kh) * 32; int _d = ((((t) & 1) * 2 + (kh)) * 8192); \
    GLDS16(Ag0 + _c, &As[_d + tid * 8]); GLDS16(Ag1 + _c, &As[_d + 4096 + tid * 8]); } while (0)
#define STG_B(t, kh) do { int _c = (t) * 64 + (kh) * 32; int _d = ((((t) & 1) * 2 + (kh)) * 8192); \
    GLDS16(Bg0 + _c, &Bs[_d + tid * 8]); GLDS16(Bg1 + _c, &Bs[_d + 4096 + tid * 8]); } while (0)

  int lswz = (l >> 1) & 3;
  int acol = ((l >> 4) ^ lswz) * 8;
  const unsigned short* Afr = &As[(wm + (l & 15)) * 32 + acol];
  const unsigned short* Bfr = &Bs[(wn + (l & 15)) * 32 + acol];

  f32x4 acc[8][4] = {};
  int nkt = K >> 6;

  STG_A(0, 0); STG_B(0, 0); STG_A(0, 1); STG_B(0, 1); STG_A(1, 0); STG_B(1, 0);
  asm volatile("s_waitcnt vmcnt(4)" ::: "memory");
  __builtin_amdgcn_s_barrier();
  __builtin_amdgcn_sched_barrier(0);

  for (int t = 0; t < nkt; ++t) {
    int cur = t & 1, rem = nkt - t;
    const unsigned short* ab = Afr + cur * 16384;
    const unsigned short* bb = Bfr + cur * 16384;
    s16x8 af[4], bf[4], afn[4], bfn[4];
    // ---- p1: (mhalf0, k0) ----
    if (t + 1 < nkt) STG_A(t + 1, 1);
#pragma unroll
    for (int nr = 0; nr < 4; ++nr) bf[nr] = *(const s16x8*)(bb + nr * 512);
#pragma unroll
    for (int mr = 0; mr < 4; ++mr) af[mr] = *(const s16x8*)(ab + mr * 512);
    __builtin_amdgcn_s_setprio(1);
#pragma unroll
    for (int mr = 0; mr < 4; ++mr)
#pragma unroll
      for (int nr = 0; nr < 4; ++nr)
        acc[mr][nr] = MFMA(af[mr], bf[nr], acc[mr][nr]);
    __builtin_amdgcn_s_setprio(0);
    // ---- p2: (mhalf1, k0) ----
    if (t + 1 < nkt) STG_B(t + 1, 1);
#pragma unroll
    for (int mr = 0; mr < 4; ++mr) af[mr] = *(const s16x8*)(ab + 2048 + mr * 512);
    __builtin_amdgcn_s_setprio(1);
#pragma unroll
    for (int mr = 0; mr < 4; ++mr)
#pragma unroll
      for (int nr = 0; nr < 4; ++nr)
        acc[mr + 4][nr] = MFMA(af[mr], bf[nr], acc[mr + 4][nr]);
    __builtin_amdgcn_s_setprio(0);
    // ---- prefetch k1(t) fragments (resident since tile entry) ----
#pragma unroll
    for (int nr = 0; nr < 4; ++nr) bfn[nr] = *(const s16x8*)(bb + 8192 + nr * 512);
#pragma unroll
    for (int mr = 0; mr < 4; ++mr) afn[mr] = *(const s16x8*)(ab + 8192 + mr * 512);
#pragma unroll
    for (int mr = 0; mr < 4; ++mr) af[mr] = *(const s16x8*)(ab + 8192 + 2048 + mr * 512);
    if (rem >= 2) { asm volatile("s_waitcnt vmcnt(4)" ::: "memory"); }
    else          { asm volatile("s_waitcnt vmcnt(0)" ::: "memory"); }
    __builtin_amdgcn_s_barrier();
    // ---- p3: (mhalf0, k1) ----
    if (t + 2 < nkt) STG_A(t + 2, 0);
    __builtin_amdgcn_s_setprio(1);
#pragma unroll
    for (int mr = 0; mr < 4; ++mr)
#pragma unroll
      for (int nr = 0; nr < 4; ++nr)
        acc[mr][nr] = MFMA(afn[mr], bfn[nr], acc[mr][nr]);
    __builtin_amdgcn_s_setprio(0);
    // ---- p4: (mhalf1, k1) ----
    if (t + 2 < nkt) STG_B(t + 2, 0);
    __builtin_amdgcn_s_setprio(1);
#pragma unroll
    for (int mr = 0; mr < 4; ++mr)
#pragma unroll
      for (int nr = 0; nr < 4; ++nr)
        acc[mr + 4][nr] = MFMA(af[mr], bfn[nr], acc[mr + 4][nr]);
    __builtin_amdgcn_s_setprio(0);
    if (rem >= 3) { asm volatile("s_waitcnt vmcnt(4)" ::: "memory"); }
    else          { asm volatile("s_waitcnt vmcnt(0)" ::: "memory"); }
    __builtin_amdgcn_s_barrier();
    __builtin_amdgcn_sched_barrier(0);
  }
#undef STG_A
#undef STG_B

  if (MODE == 4) {
    if (nt < 8) {
      unsigned short* dst = (nt < 4) ? Cq : Ck;
      int cb = (nt < 4) ? 0 : 1024;
#pragma unroll
      for (int mr = 0; mr < 8; ++mr) {
        int rb = m0 + wm + mr * 16 + (l >> 4) * 4;
#pragma unroll
        for (int nr = 0; nr < 4; ++nr) {
          int col = n0 + wn + nr * 16 + (l & 15);
          float bv = bias[col];
#pragma unroll
          for (int j = 0; j < 4; ++j)
            dst[(size_t)(rb + j) * 1024 + (col - cb)] = f2bf(acc[mr][nr][j] + bv);
        }
      }
    } else {  // V: scatter transposed into Cv[bh][d][sigma(s)], sigma = swap bits 2<->3
#pragma unroll
      for (int mr = 0; mr < 8; ++mr) {
        int rb = m0 + wm + mr * 16 + (l >> 4) * 4;
        int b2 = rb >> 11, s2 = rb & 2047;
        int s2p = (s2 & ~12) | ((s2 & 4) << 1) | ((s2 & 8) >> 1);
#pragma unroll
        for (int nr = 0; nr < 4; ++nr) {
          int col2 = n0 - 2048 + wn + nr * 16 + (l & 15);
          float bv = bias[col2 + 2048];
          u16x4 pk;
#pragma unroll
          for (int j = 0; j < 4; ++j) ((unsigned short*)&pk)[j] = f2bf(acc[mr][nr][j] + bv);
          *(u16x4*)(Cv + ((size_t)((b2 * 16 + (col2 >> 6)) * 64 + (col2 & 63))) * 2048 + s2p) = pk;
        }
      }
    }
    return;
  }
  unsigned short* Cbz = (MODE == 3) ? (Cb + zstride * blockIdx.z) : Cb;
#pragma unroll
  for (int mr = 0; mr < 8; ++mr) {
    int rb = m0 + wm + mr * 16 + (l >> 4) * 4;
#pragma unroll
    for (int nr = 0; nr < 4; ++nr) {
      int col = n0 + wn + nr * 16 + (l & 15);
      float bv = (MODE == 3) ? 0.f : bias[col];
#pragma unroll
      for (int j = 0; j < 4; ++j) {
        float v = acc[mr][nr][j] + bv;
        size_t off = (size_t)(rb + j) * ldc + col;
        if (MODE == 1) v = fmaxf(v, 0.f);
        Cbz[off] = f2bf(v);
      }
    }
  }
}

// ---------------- FF2 split-K=4 reduce (row-interleaved bf16 slices) ----------------
__global__ __launch_bounds__(256) void k_ff2_reduce(
    unsigned short* __restrict__ slices, const float* __restrict__ bias,
    const unsigned short* __restrict__ resid, float* __restrict__ partials) {
  __shared__ float red[8];
  int i = blockIdx.x;
  size_t rb = (size_t)i * 4096;
  int c = threadIdx.x * 4;
  u16x4 a0 = *(const u16x4*)(slices + rb + c);
  u16x4 a1 = *(const u16x4*)(slices + rb + 1024 + c);
  u16x4 a2 = *(const u16x4*)(slices + rb + 2048 + c);
  u16x4 a3 = *(const u16x4*)(slices + rb + 3072 + c);
  float4 bv = *(const float4*)(bias + c);
  u16x4 rv = *(const u16x4*)(resid + (size_t)i * 1024 + c);
  float4 o;
  o.x = bf2f(a0.x) + bf2f(a1.x) + bf2f(a2.x) + bf2f(a3.x) + bv.x + bf2f(rv.x);
  o.y = bf2f(a0.y) + bf2f(a1.y) + bf2f(a2.y) + bf2f(a3.y) + bv.y + bf2f(rv.y);
  o.z = bf2f(a0.z) + bf2f(a1.z) + bf2f(a2.z) + bf2f(a3.z) + bv.z + bf2f(rv.z);
  o.w = bf2f(a0.w) + bf2f(a1.w) + bf2f(a2.w) + bf2f(a3.w) + bv.w + bf2f(rv.w);
  __syncthreads();
  *(float4*)((float*)slices + (size_t)i * 2048 + c) = o;
  float bsum = o.x + o.y + o.z + o.w;
  float bsq = o.x * o.x + o.y * o.y + o.z * o.z + o.w * o.w;
  int wv = threadIdx.x >> 6, lv = threadIdx.x & 63;
#pragma unroll
  for (int mk = 1; mk < 64; mk <<= 1) { bsum += __shfl_xor(bsum, mk); bsq += __shfl_xor(bsq, mk); }
  if (lv == 0) { red[wv] = bsum; red[4 + wv] = bsq; }
  __syncthreads();
  if (threadIdx.x == 0) {
    partials[i * 2] = red[0] + red[1] + red[2] + red[3];
    partials[i * 2 + 1] = red[4] + red[5] + red[6] + red[7];
  }
}

// ---------------- causal flash attention, QBLK=128 (4 waves), 32x32 MFMA ----------------
// round-14 proven + deeper K-prefetch: STG_K(T+1) issues BEFORE the top wait
// (its buffer drained at BODY(T-1)'s mid lgkm+barrier; BODY(T-1)'s end barrier
// precedes the issue for all waves). Top wait becomes vmcnt(4): retires K(T)
// and all older (incl. V(T-1)), leaves {V(T), K(T+1)} in flight.
__global__ __launch_bounds__(256, 2) void k_attn(
    const unsigned short* __restrict__ Qg, const unsigned short* __restrict__ Kg,
    const unsigned short* __restrict__ Vt,
    const unsigned short* __restrict__ xbg, unsigned short* __restrict__ hpre,
    float* __restrict__ partials, int S, int H) {
  __shared__ __align__(16) unsigned short Ks[2][4096];
  __shared__ __align__(16) unsigned short Vs[2][4096];
  __shared__ float ascr[4][32];
  __shared__ float red[8];
  int bh = blockIdx.x, b = bh >> 4, h = bh & 15;
  int y = (int)blockIdx.y;
  int qt = (y < 8) ? (15 - y) : (y - 8);
  int tid = threadIdx.x, w = tid >> 6, l = tid & 63;
  int lo = l & 31, hi5 = l >> 5;
  const int U = H * 64;
  const unsigned short* Qb = Qg + (size_t)(b * S) * 1024 + h * 64;
  const unsigned short* Kb = Kg + (size_t)(b * S) * 1024 + h * 64;
  const unsigned short* Vb = Vt + (size_t)bh * 64 * S;
  int tl = 2 * qt + 1;

  int sg_r[2], sg_c[2];
#pragma unroll
  for (int it = 0; it < 2; ++it) {
    int g = it * 256 + tid;
    sg_r[it] = g >> 3;
    sg_c[it] = ((g & 7) ^ ((g >> 3) & 7)) * 8;
  }
#define STG_K(kt) do { int _kn = (kt) * 64, _bf = (kt) & 1; \
    _Pragma("unroll") for (int it = 0; it < 2; ++it) \
      GLDS16(Kb + (size_t)(_kn + sg_r[it]) * 1024 + sg_c[it], &Ks[_bf][(it * 256 + tid) * 8]); } while (0)
#define STG_V(kt) do { int _kn = (kt) * 64, _bf = (kt) & 1; \
    _Pragma("unroll") for (int it = 0; it < 2; ++it) \
      GLDS16(Vb + (size_t)sg_r[it] * S + _kn + sg_c[it], &Vs[_bf][(it * 256 + tid) * 8]); } while (0)

  int qrow = qt * 128 + w * 32 + lo;
  s16x8 qf[4];
#pragma unroll
  for (int s = 0; s < 4; ++s)
    qf[s] = *(const s16x8*)(Qb + (size_t)qrow * 1024 + s * 16 + hi5 * 8);

  int krow[16];
#pragma unroll
  for (int r = 0; r < 16; ++r) krow[r] = (r & 3) + 8 * (r >> 2) + 4 * hi5;
  int wq = w * 32 + lo;

  f32x16 o0 = {}, o1 = {};
  float m = -1e30f, lsum = 0.f;
  f32x16 scA0, scA1, scB0, scB1;

#define MBASE(T) (((T) >= 2 * qt) ? ((T) * 64 - qt * 128) : -1)

#define QK_T(S0, S1, T) do { \
    S0 = (f32x16)(0.0f); S1 = (f32x16)(0.0f); \
    const unsigned short* _kp = &Ks[(T) & 1][0]; \
    __builtin_amdgcn_s_setprio(1); \
    _Pragma("unroll") for (int s = 0; s < 4; ++s) { \
      int gc = ((2 * s + hi5) ^ (lo & 7)) * 8; \
      s16x8 kf0 = *(const s16x8*)&_kp[lo * 64 + gc]; \
      s16x8 kf1 = *(const s16x8*)&_kp[(32 + lo) * 64 + gc]; \
      S0 = MFMA32(kf0, qf[s], S0); \
      S1 = MFMA32(kf1, qf[s], S1); } \
    __builtin_amdgcn_s_setprio(0); } while (0)

#define SMPV(S0, S1, T, MB) do { \
    if ((MB) >= 0) { \
      _Pragma("unroll") for (int r = 0; r < 16; ++r) { \
        if (krow[r] + (MB) > wq) S0[r] = -1e30f; \
        if (krow[r] + 32 + (MB) > wq) S1[r] = -1e30f; } } \
    float mx = S0[0]; \
    _Pragma("unroll") for (int r = 1; r < 16; ++r) mx = fmaxf(mx, S0[r]); \
    _Pragma("unroll") for (int r = 0; r < 16; ++r) mx = fmaxf(mx, S1[r]); \
    mx = fmaxf(mx, __shfl_xor(mx, 32)); \
    if (__ballot(mx > m + 11.5415603f)) { \
      float mnew = fmaxf(m, mx); \
      float alpha = __builtin_amdgcn_exp2f(m - mnew); \
      m = mnew; lsum *= alpha; \
      if (l < 32) ascr[w][lo] = alpha; \
      _Pragma("unroll") for (int r = 0; r < 16; ++r) { \
        float aj = ascr[w][krow[r]]; o0[r] *= aj; o1[r] *= aj; } } \
    float rs = 0.f; unsigned wk0[8], wk1[8]; \
    _Pragma("unroll") for (int j = 0; j < 8; ++j) { \
      float p0 = __builtin_amdgcn_exp2f(S0[2 * j] - m); \
      float p1 = __builtin_amdgcn_exp2f(S0[2 * j + 1] - m); \
      rs += p0 + p1; wk0[j] = (unsigned)f2bf(p0) | ((unsigned)f2bf(p1) << 16); \
      float p2 = __builtin_amdgcn_exp2f(S1[2 * j] - m); \
      float p3 = __builtin_amdgcn_exp2f(S1[2 * j + 1] - m); \
      rs += p2 + p3; wk1[j] = (unsigned)f2bf(p2) | ((unsigned)f2bf(p3) << 16); } \
    rs += __shfl_xor(rs, 32); lsum += rs; \
    __builtin_amdgcn_s_setprio(1); \
    _Pragma("unroll") for (int s = 0; s < 4; ++s) { \
      u32x4 paw; \
      if (s == 0)      { paw.x = wk0[0]; paw.y = wk0[1]; paw.z = wk0[2]; paw.w = wk0[3]; } \
      else if (s == 1) { paw.x = wk0[4]; paw.y = wk0[5]; paw.z = wk0[6]; paw.w = wk0[7]; } \
      else if (s == 2) { paw.x = wk1[0]; paw.y = wk1[1]; paw.z = wk1[2]; paw.w = wk1[3]; } \
      else             { paw.x = wk1[4]; paw.y = wk1[5]; paw.z = wk1[6]; paw.w = wk1[7]; } \
      s16x8 pa = *(s16x8*)&paw; \
      int gc = ((2 * s + hi5) ^ (lo & 7)) * 8; \
      s16x8 vf0 = *(const s16x8*)&Vs[(T) & 1][lo * 64 + gc]; \
      s16x8 vf1 = *(const s16x8*)&Vs[(T) & 1][(32 + lo) * 64 + gc]; \
      o0 = MFMA32(pa, vf0, o0); \
      o1 = MFMA32(pa, vf1, o1); } \
    __builtin_amdgcn_s_setprio(0); \
  } while (0)

#define BODY(O0, O1, I0, I1, T) do { \
    if ((T) + 1 <= tl) STG_K((T) + 1); \
    asm volatile("s_waitcnt vmcnt(4)" ::: "memory"); \
    __builtin_amdgcn_s_barrier(); \
    __builtin_amdgcn_sched_barrier(0); \
    QK_T(O0, O1, (T)); \
    SMPV(I0, I1, (T) - 1, MBASE((T) - 1)); \
    asm volatile("s_waitcnt lgkmcnt(0)" ::: "memory"); \
    __builtin_amdgcn_sched_barrier(0); \
    __builtin_amdgcn_s_barrier(); \
    __builtin_amdgcn_sched_barrier(0); \
    if ((T) + 1 <= tl) STG_V((T) + 1); \
  } while (0)

  STG_K(0); STG_V(0); STG_K(1); STG_V(1);
  asm volatile("s_waitcnt vmcnt(4)" ::: "memory");
  __builtin_amdgcn_s_barrier();
  __builtin_amdgcn_sched_barrier(0);
  QK_T(scA0, scA1, 0);
  asm volatile("s_waitcnt lgkmcnt(0)" ::: "memory");
  __builtin_amdgcn_sched_barrier(0);

  int t = 1;
  for (; t + 1 <= tl; t += 2) {
    BODY(scB0, scB1, scA0, scA1, t);
    BODY(scA0, scA1, scB0, scB1, t + 1);
  }
  if (t <= tl) {
    BODY(scB0, scB1, scA0, scA1, t);
    asm volatile("s_waitcnt vmcnt(0)" ::: "memory");
    __builtin_amdgcn_sched_barrier(0);
    SMPV(scB0, scB1, tl, MBASE(tl));
  } else {
    asm volatile("s_waitcnt vmcnt(0)" ::: "memory");
    __builtin_amdgcn_sched_barrier(0);
    SMPV(scA0, scA1, tl, MBASE(tl));
  }

  // ---- epilogue: O/l + bf16 x residual -> bf16, LN partials ----
  if (l < 32) ascr[w][lo] = 1.f / lsum;
  float bsum = 0.f, bsq = 0.f;
  unsigned short* hb = hpre + (size_t)(b * S) * U + h * 64;
  const unsigned short* xb = xbg + (size_t)(b * S) * U + h * 64;
#pragma unroll
  for (int r = 0; r < 16; ++r) {
    float inv = ascr[w][krow[r]];
    int srow = qt * 128 + w * 32 + krow[r];
    size_t base = (size_t)srow * U + lo;
    float v0 = o0[r] * inv + bf2f(xb[base]);
    float v1 = o1[r] * inv + bf2f(xb[base + 32]);
    hb[base] = f2bf(v0);
    hb[base + 32] = f2bf(v1);
    bsum += v0 + v1; bsq += v0 * v0 + v1 * v1;
  }
#pragma unroll
  for (int mk = 1; mk < 64; mk <<= 1) { bsum += __shfl_xor(bsum, mk); bsq += __shfl_xor(bsq, mk); }
  if (l == 0) { red[w * 2] = bsum; red[w * 2 + 1] = bsq; }
  __syncthreads();
  if (tid == 0) {
    int pi = b * (H * 16) + h * 16 + qt;
    partials[pi * 2] = red[0] + red[2] + red[4] + red[6];
    partials[pi * 2 + 1] = red[1] + red[3] + red[5] + red[7];
  }
#undef STG_K
#undef STG_V
#undef QK_T
#undef SMPV
#undef BODY
#undef MBASE
}

// ---------------- LN over (S,U) per batch ----------------
__global__ __launch_bounds__(256) void k_ln_stats(const float* __restrict__ partials, int nper,
                                                  float* __restrict__ stats, float invN) {
  int b = blockIdx.x, tid = threadIdx.x;
  float s = 0.f, q = 0.f;
  for (int i = tid; i < nper; i += 256) { s += partials[(b * nper + i) * 2]; q += partials[(b * nper + i) * 2 + 1]; }
#pragma unroll
  for (int mk = 1; mk < 64; mk <<= 1) { s += __shfl_xor(s, mk); q += __shfl_xor(q, mk); }
  __shared__ float red[8];
  int w = tid >> 6, l = tid & 63;
  if (l == 0) { red[w] = s; red[4 + w] = q; }
  __syncthreads();
  if (tid == 0) {
    s = red[0] + red[1] + red[2] + red[3];
    q = red[4] + red[5] + red[6] + red[7];
    float m = s * invN, var = q * invN - m * m;
    stats[b * 2] = m; stats[b * 2 + 1] = rsqrtf(var + 1e-5f);
  }
}

// LN apply from bf16 src -> bf16 out (LN1 path)
__global__ __launch_bounds__(256) void k_ln_apply_b(
    const unsigned short* __restrict__ src, const float* __restrict__ stats,
    const float* __restrict__ g, const float* __restrict__ bt,
    unsigned short* __restrict__ outb, int SU) {
  int b = blockIdx.y;
  int idx = (blockIdx.x * 256 + threadIdx.x) * 4;
  float m = stats[b * 2], r = stats[b * 2 + 1];
  u16x4 v4 = *(const u16x4*)(src + (size_t)b * SU + idx);
  float4 gg = *(const float4*)(g + idx);
  float4 bb = *(const float4*)(bt + idx);
  u16x4 ob;
  ob.x = f2bf((bf2f(v4.x) - m) * r * gg.x + bb.x);
  ob.y = f2bf((bf2f(v4.y) - m) * r * gg.y + bb.y);
  ob.z = f2bf((bf2f(v4.z) - m) * r * gg.z + bb.z);
  ob.w = f2bf((bf2f(v4.w) - m) * r * gg.w + bb.w);
  *(u16x4*)(outb + (size_t)b * SU + idx) = ob;
}

// LN apply from stride-2048 f32 rows (FF2 reduce output) -> d_out
__global__ __launch_bounds__(256) void k_ln_apply2(
    const float* __restrict__ src, const float* __restrict__ stats,
    const float* __restrict__ g, const float* __restrict__ bt,
    float* __restrict__ outf) {
  int b = blockIdx.y;
  int row = blockIdx.x;
  int grow = b * 2048 + row;
  int c = threadIdx.x * 4;
  float m = stats[b * 2], r = stats[b * 2 + 1];
  float4 v = *(const float4*)(src + (size_t)grow * 2048 + c);
  float4 gg = *(const float4*)(g + (size_t)row * 1024 + c);
  float4 bb = *(const float4*)(bt + (size_t)row * 1024 + c);
  float4 o;
  o.x = (v.x - m) * r * gg.x + bb.x;
  o.y = (v.y - m) * r * gg.y + bb.y;
  o.z = (v.z - m) * r * gg.z + bb.z;
  o.w = (v.w - m) * r * gg.w + bb.w;
  *(float4*)(outf + (size_t)grow * 1024 + c) = o;
}

extern "C" void kernel_launch(void* const* d_in, const int* in_sizes, int n_in,
                              void* d_out, int out_size, void* d_ws, size_t ws_size,
                              hipStream_t stream) {
  (void)in_sizes; (void)n_in; (void)out_size; (void)ws_size;
  const int S = 2048, H = 16;
  const float* x   = (const float*)d_in[0];
  const float* wq  = (const float*)d_in[1];
  const float* bq  = (const float*)d_in[2];
  const float* wk  = (const float*)d_in[3];
  const float* bk  = (const float*)d_in[4];
  const float* wv  = (const float*)d_in[5];
  const float* bv  = (const float*)d_in[6];
  const float* wf1 = (const float*)d_in[7];
  const float* bf1 = (const float*)d_in[8];
  const float* wf2 = (const float*)d_in[9];
  const float* bf2 = (const float*)d_in[10];
  const float* lng = (const float*)d_in[11];
  const float* lnb = (const float*)d_in[12];
  const float* ffg = (const float*)d_in[13];
  const float* ffb = (const float*)d_in[14];

  char* ws = (char*)d_ws;
  unsigned short* wqkvT = (unsigned short*)(ws);              // 3072x1024 bf16 (dead after QKV)
  unsigned short* wf1T  = (unsigned short*)(ws + 6291456);    // 4096x1024 bf16 (dead after FF1)
  unsigned short* wf2T  = (unsigned short*)(ws + 14680064);   // 1024x4096 bf16
  unsigned short* xb    = (unsigned short*)(ws + 23068672);   // 4096x1024 bf16 (live through attn)
  unsigned short* qb    = (unsigned short*)(ws + 31457280);   // 4096x1024 bf16 Q (dead after attn)
  unsigned short* kbuf  = (unsigned short*)(ws + 39845888);   // 4096x1024 bf16 K (dead after attn)
  unsigned short* vt    = (unsigned short*)(ws + 56623104);   // 32x64x2048 bf16 V^T sigma (dead after attn)
  unsigned short* h1b   = (unsigned short*)(ws + 65011712);   // 4096x1024 bf16 (LN1 out)
  unsigned short* hpreb = (unsigned short*)(ws + 73400320);   // 4096x1024 bf16 (attn out, dead after LN1)
  unsigned short* ff2s  = (unsigned short*)(ws + 73400320);   // FF2 slices: 4096x4096 bf16 (over hpreb)
  unsigned short* f1b   = (unsigned short*)(ws + 23068672);   // 4096x4096 bf16 (over xb+qb+kbuf)
  float* biasqkv        = (float*)(ws + 106954752);           // 3072 f32
  float* part_attn      = (float*)(ws + 106967040);           // 2*256*2 f32
  float* stats1         = (float*)(ws + 106977280);           // 2*2 f32
  float* ffpart2        = (float*)(ws);                       // 4096*2 f32 (over wqkvT, dead)
  float* stats2         = (float*)(ws + 65536);               // 2*2 f32 (over wqkvT, dead)

  // Q path pre-scaled by 0.125 * log2(e) for log2-domain softmax
  const float qscale = 0.125f * 1.44269504f;
  k_f32_to_bf16<<<4096, 256, 0, stream>>>(x, xb, 4096 * 1024 / 4);
  k_transpose_w3<<<dim3(16, 16, 3), 256, 0, stream>>>(wq, wk, wv, wqkvT, qscale);
  k_transpose_w<<<dim3(16, 64), 256, 0, stream>>>(wf1, wf1T, 1024, 4096, 1.0f);
  k_transpose_w<<<dim3(64, 16), 256, 0, stream>>>(wf2, wf2T, 4096, 1024, 1.0f);
  k_concat3<<<12, 256, 0, stream>>>(bq, bk, bv, biasqkv, 1024, qscale);

  // QKV projection: split outputs Q | K | V^T(sigma) (no separate transpose pass)
  k_gemm8<4><<<dim3(192, 1, 1), 512, 0, stream>>>(xb, 1024, wqkvT, 1024, biasqkv,
      nullptr, nullptr, 0, 1024, 12, 0, qb, kbuf, vt);

  // causal flash attention (QBLK=128, 4 waves) + bf16 x residual -> bf16 + LN1 partials
  k_attn<<<dim3(32, 16), 256, 0, stream>>>(qb, kbuf, vt, xb, hpreb, part_attn, S, H);

  // LN1 -> bf16
  k_ln_stats<<<2, 256, 0, stream>>>(part_attn, 256, stats1, 1.f / (2048.f * 1024.f));
  k_ln_apply_b<<<dim3(2048, 2), 256, 0, stream>>>(hpreb, stats1, lng, lnb, h1b, S * 1024);

  // FF1: (4096x1024) @ (1024x4096), ReLU
  k_gemm8<1><<<dim3(256, 1, 1), 512, 0, stream>>>(h1b, 1024, wf1T, 1024, bf1,
      f1b, nullptr, 4096, 1024, 16, 0, nullptr, nullptr, nullptr);

  // FF2: (4096x4096) @ (4096x1024), split-K=4, bf16 row-interleaved slices
  k_gemm8<3><<<dim3(64, 1, 4), 512, 0, stream>>>(f1b, 4096, wf2T, 4096, nullptr,
      ff2s, nullptr, 4096, 1024, 4, 1024, nullptr, nullptr, nullptr);

  // reduce slices + bias + bf16 residual -> f32 rows (stride 2048), LN2 partials
  k_ff2_reduce<<<4096, 256, 0, stream>>>(ff2s, bf2, h1b, ffpart2);

  // LN2 -> d_out (fp32)
  k_ln_stats<<<2, 256, 0, stream>>>(ffpart2, 2048, stats2, 1.f / (2048.f * 1024.f));
  k_ln_apply2<<<dim3(2048, 2), 256, 0, stream>>>((float*)ff2s, stats2, ffg, ffb, (float*)d_out);
}

// Round 18
// 204.824 us; speedup vs baseline: 1.0429x; 1.0385x over previous
//
#include <hip/hip_runtime.h>
#include <hip/hip_bf16.h>

typedef short s16x8 __attribute__((ext_vector_type(8)));
typedef float f32x4 __attribute__((ext_vector_type(4)));
typedef float f32x16 __attribute__((ext_vector_type(16)));
typedef unsigned short u16x4 __attribute__((ext_vector_type(4)));
typedef unsigned u32x4 __attribute__((ext_vector_type(4)));

#define DEV static __device__ __forceinline__

DEV unsigned short f2bf(float f) {  // native cast -> compiler packs pairs into v_cvt_pk_bf16_f32
  __hip_bfloat16 h = __float2bfloat16(f);
  return *reinterpret_cast<unsigned short*>(&h);
}
DEV float bf2f(unsigned short u) {
  union { unsigned u; float f; } v; v.u = (unsigned)u << 16; return v.f;
}

#define GLDS16(src, dst) \
  __builtin_amdgcn_global_load_lds((const __attribute__((address_space(1))) void*)(src), \
                                   (__attribute__((address_space(3))) void*)(dst), 16, 0, 0)

#define MFMA(a, b, c) __builtin_amdgcn_mfma_f32_16x16x32_bf16((a), (b), (c), 0, 0, 0)
#define MFMA32(a, b, c) __builtin_amdgcn_mfma_f32_32x32x16_bf16((a), (b), (c), 0, 0, 0)

// ---------------- fused preprocessing: x->bf16 | 5 weight transposes | bias concat ----------------
// One launch, blockIdx.x ranges (wave-uniform branch):
//   [0,4096)          x (4096x1024 f32) -> xb bf16
//   [4096,4864)       wq|wk|wv (1024^2) -> wqkvT (N,K) bf16 (wq scaled)
//   [4864,5888)       wf1 (1024x4096)   -> wf1T  (N,K) bf16
//   [5888,6912)       wf2 (4096x1024)   -> wf2T  (N,K) bf16
//   [6912,6924)       bias concat (bq scaled)
DEV void tr_tile(const float* __restrict__ W, unsigned short* __restrict__ Wt,
                 int K, int N, int k0, int n0, float scale, float (*t)[65]) {
  int tid = threadIdx.x;
#pragma unroll
  for (int i = 0; i < 16; ++i) {
    int idx = tid + i * 256; int r = idx >> 6, c = idx & 63;
    t[r][c] = W[(size_t)(k0 + r) * N + (n0 + c)];
  }
  __syncthreads();
#pragma unroll
  for (int i = 0; i < 16; ++i) {
    int idx = tid + i * 256; int r = idx >> 6, c = idx & 63;
    Wt[(size_t)(n0 + r) * K + (k0 + c)] = f2bf(t[c][r] * scale);
  }
}

__global__ __launch_bounds__(256) void k_prep(
    const float* __restrict__ x, unsigned short* __restrict__ xb,
    const float* __restrict__ wq, const float* __restrict__ wk,
    const float* __restrict__ wv, unsigned short* __restrict__ wqkvT,
    const float* __restrict__ wf1, unsigned short* __restrict__ wf1T,
    const float* __restrict__ wf2, unsigned short* __restrict__ wf2T,
    const float* __restrict__ bq, const float* __restrict__ bk,
    const float* __restrict__ bv, float* __restrict__ biasqkv, float qscale) {
  __shared__ float t[64][65];
  int bid = blockIdx.x;
  if (bid < 4096) {                       // x -> bf16 (float4 / u16x4)
    int i = bid * 256 + threadIdx.x;
    float4 v = ((const float4*)x)[i];
    u16x4 o; o.x = f2bf(v.x); o.y = f2bf(v.y); o.z = f2bf(v.z); o.w = f2bf(v.w);
    ((u16x4*)xb)[i] = o;
    return;
  }
  bid -= 4096;
  if (bid < 768) {                        // wq|wk|wv transpose (256 tiles each)
    int z = bid >> 8, tt = bid & 255;
    const float* W = (z == 0) ? wq : (z == 1) ? wk : wv;
    tr_tile(W, wqkvT + (size_t)z * 1024 * 1024, 1024, 1024,
            (tt >> 4) * 64, (tt & 15) * 64, (z == 0) ? qscale : 1.0f, t);
    return;
  }
  bid -= 768;
  if (bid < 1024) {                       // wf1 transpose (K=1024, N=4096)
    tr_tile(wf1, wf1T, 1024, 4096, (bid & 15) * 64, (bid >> 4) * 64, 1.0f, t);
    return;
  }
  bid -= 1024;
  if (bid < 1024) {                       // wf2 transpose (K=4096, N=1024)
    tr_tile(wf2, wf2T, 4096, 1024, (bid & 63) * 64, (bid >> 6) * 64, 1.0f, t);
    return;
  }
  bid -= 1024;
  {                                       // bias concat (12 blocks, 3072 elems)
    int i = bid * 256 + threadIdx.x;
    int j = (i < 1024) ? i : (i < 2048 ? i - 1024 : i - 2048);
    biasqkv[i] = (i < 1024) ? bq[j] * qscale : (i < 2048 ? bk[j] : bv[j]);
  }
}

// ---------------- 256x256 4-phase pipelined GEMM (round-14 proven best) ----------------
// BK=64, two k-half granules, 2 LDS tile-buffers, counted vmcnt(4), setprio
// clusters, XOR-swizzled LDS (both-sides), XCD block swizzle. k1-half fragment
// ds_reads prefetched BEFORE the mid barrier (resident since tile entry).
// MODE 0: bias->bf16. MODE 1: bias+relu->bf16. MODE 3: raw bf16 partial at
// Cb + z*zstride. MODE 4: QKV split: nt<4 -> Cq, nt<8 -> Ck, else V scattered
// transposed into Cv[bh][d][sigma(s)] (sigma = swap bits 2<->3 of s%16).
template <int MODE>
__global__ __launch_bounds__(512, 2) void k_gemm8(
    const unsigned short* __restrict__ A, int lda,
    const unsigned short* __restrict__ Bt, int ldb,
    const float* __restrict__ bias,
    unsigned short* __restrict__ Cb, float* __restrict__ Cf, int ldc,
    int K, int nnt, size_t zstride,
    unsigned short* __restrict__ Cq, unsigned short* __restrict__ Ck,
    unsigned short* __restrict__ Cv) {
  __shared__ __align__(16) unsigned short As[2 * 2 * 8192];  // [buf][kh][256][32]
  __shared__ __align__(16) unsigned short Bs[2 * 2 * 8192];
  int nwg = gridDim.x;
  int bid = blockIdx.x;
  int cpx = nwg >> 3;
  int swz = (bid & 7) * cpx + (bid >> 3);
  int mt = swz / nnt, nt = swz % nnt;
  int m0 = mt * 256, n0 = nt * 256;
  int tid = threadIdx.x, w = tid >> 6, l = tid & 63;
  int wm = (w >> 2) * 128, wn = (w & 3) * 64;
  int kb = blockIdx.z * K;

  int sr = tid >> 2;
  int gsrc = (tid & 3) ^ ((sr >> 1) & 3);
  const unsigned short* Ag0 = A + (size_t)(m0 + sr) * lda + kb + gsrc * 8;
  const unsigned short* Ag1 = Ag0 + (size_t)128 * lda;
  const unsigned short* Bg0 = Bt + (size_t)(n0 + sr) * ldb + kb + gsrc * 8;
  const unsigned short* Bg1 = Bg0 + (size_t)128 * ldb;

#define STG_A(t, kh) do { int _c = (t) * 64 + (kh) * 32; int _d = ((((t) & 1) * 2 + (kh)) * 8192); \
    GLDS16(Ag0 + _c, &As[_d + tid * 8]); GLDS16(Ag1 + _c, &As[_d + 4096 + tid * 8]); } while (0)
#define STG_B(t, kh) do { int _c = (t) * 64 + (kh) * 32; int _d = ((((t) & 1) * 2 + (kh)) * 8192); \
    GLDS16(Bg0 + _c, &Bs[_d + tid * 8]); GLDS16(Bg1 + _c, &Bs[_d + 4096 + tid * 8]); } while (0)

  int lswz = (l >> 1) & 3;
  int acol = ((l >> 4) ^ lswz) * 8;
  const unsigned short* Afr = &As[(wm + (l & 15)) * 32 + acol];
  const unsigned short* Bfr = &Bs[(wn + (l & 15)) * 32 + acol];

  f32x4 acc[8][4] = {};
  int nkt = K >> 6;

  STG_A(0, 0); STG_B(0, 0); STG_A(0, 1); STG_B(0, 1); STG_A(1, 0); STG_B(1, 0);
  asm volatile("s_waitcnt vmcnt(4)" ::: "memory");
  __builtin_amdgcn_s_barrier();
  __builtin_amdgcn_sched_barrier(0);

  for (int t = 0; t < nkt; ++t) {
    int cur = t & 1, rem = nkt - t;
    const unsigned short* ab = Afr + cur * 16384;
    const unsigned short* bb = Bfr + cur * 16384;
    s16x8 af[4], bf[4], afn[4], bfn[4];
    // ---- p1: (mhalf0, k0) ----
    if (t + 1 < nkt) STG_A(t + 1, 1);
#pragma unroll
    for (int nr = 0; nr < 4; ++nr) bf[nr] = *(const s16x8*)(bb + nr * 512);
#pragma unroll
    for (int mr = 0; mr < 4; ++mr) af[mr] = *(const s16x8*)(ab + mr * 512);
    __builtin_amdgcn_s_setprio(1);
#pragma unroll
    for (int mr = 0; mr < 4; ++mr)
#pragma unroll
      for (int nr = 0; nr < 4; ++nr)
        acc[mr][nr] = MFMA(af[mr], bf[nr], acc[mr][nr]);
    __builtin_amdgcn_s_setprio(0);
    // ---- p2: (mhalf1, k0) ----
    if (t + 1 < nkt) STG_B(t + 1, 1);
#pragma unroll
    for (int mr = 0; mr < 4; ++mr) af[mr] = *(const s16x8*)(ab + 2048 + mr * 512);
    __builtin_amdgcn_s_setprio(1);
#pragma unroll
    for (int mr = 0; mr < 4; ++mr)
#pragma unroll
      for (int nr = 0; nr < 4; ++nr)
        acc[mr + 4][nr] = MFMA(af[mr], bf[nr], acc[mr + 4][nr]);
    __builtin_amdgcn_s_setprio(0);
    // ---- prefetch k1(t) fragments (resident since tile entry) ----
#pragma unroll
    for (int nr = 0; nr < 4; ++nr) bfn[nr] = *(const s16x8*)(bb + 8192 + nr * 512);
#pragma unroll
    for (int mr = 0; mr < 4; ++mr) afn[mr] = *(const s16x8*)(ab + 8192 + mr * 512);
#pragma unroll
    for (int mr = 0; mr < 4; ++mr) af[mr] = *(const s16x8*)(ab + 8192 + 2048 + mr * 512);
    if (rem >= 2) { asm volatile("s_waitcnt vmcnt(4)" ::: "memory"); }
    else          { asm volatile("s_waitcnt vmcnt(0)" ::: "memory"); }
    __builtin_amdgcn_s_barrier();
    // ---- p3: (mhalf0, k1) ----
    if (t + 2 < nkt) STG_A(t + 2, 0);
    __builtin_amdgcn_s_setprio(1);
#pragma unroll
    for (int mr = 0; mr < 4; ++mr)
#pragma unroll
      for (int nr = 0; nr < 4; ++nr)
        acc[mr][nr] = MFMA(afn[mr], bfn[nr], acc[mr][nr]);
    __builtin_amdgcn_s_setprio(0);
    // ---- p4: (mhalf1, k1) ----
    if (t + 2 < nkt) STG_B(t + 2, 0);
    __builtin_amdgcn_s_setprio(1);
#pragma unroll
    for (int mr = 0; mr < 4; ++mr)
#pragma unroll
      for (int nr = 0; nr < 4; ++nr)
        acc[mr + 4][nr] = MFMA(af[mr], bfn[nr], acc[mr + 4][nr]);
    __builtin_amdgcn_s_setprio(0);
    if (rem >= 3) { asm volatile("s_waitcnt vmcnt(4)" ::: "memory"); }
    else          { asm volatile("s_waitcnt vmcnt(0)" ::: "memory"); }
    __builtin_amdgcn_s_barrier();
    __builtin_amdgcn_sched_barrier(0);
  }
#undef STG_A
#undef STG_B

  if (MODE == 4) {
    if (nt < 8) {
      unsigned short* dst = (nt < 4) ? Cq : Ck;
      int cb = (nt < 4) ? 0 : 1024;
#pragma unroll
      for (int mr = 0; mr < 8; ++mr) {
        int rb = m0 + wm + mr * 16 + (l >> 4) * 4;
#pragma unroll
        for (int nr = 0; nr < 4; ++nr) {
          int col = n0 + wn + nr * 16 + (l & 15);
          float bv = bias[col];
#pragma unroll
          for (int j = 0; j < 4; ++j)
            dst[(size_t)(rb + j) * 1024 + (col - cb)] = f2bf(acc[mr][nr][j] + bv);
        }
      }
    } else {  // V: scatter transposed into Cv[bh][d][sigma(s)], sigma = swap bits 2<->3
#pragma unroll
      for (int mr = 0; mr < 8; ++mr) {
        int rb = m0 + wm + mr * 16 + (l >> 4) * 4;
        int b2 = rb >> 11, s2 = rb & 2047;
        int s2p = (s2 & ~12) | ((s2 & 4) << 1) | ((s2 & 8) >> 1);
#pragma unroll
        for (int nr = 0; nr < 4; ++nr) {
          int col2 = n0 - 2048 + wn + nr * 16 + (l & 15);
          float bv = bias[col2 + 2048];
          u16x4 pk;
#pragma unroll
          for (int j = 0; j < 4; ++j) ((unsigned short*)&pk)[j] = f2bf(acc[mr][nr][j] + bv);
          *(u16x4*)(Cv + ((size_t)((b2 * 16 + (col2 >> 6)) * 64 + (col2 & 63))) * 2048 + s2p) = pk;
        }
      }
    }
    return;
  }
  unsigned short* Cbz = (MODE == 3) ? (Cb + zstride * blockIdx.z) : Cb;
#pragma unroll
  for (int mr = 0; mr < 8; ++mr) {
    int rb = m0 + wm + mr * 16 + (l >> 4) * 4;
#pragma unroll
    for (int nr = 0; nr < 4; ++nr) {
      int col = n0 + wn + nr * 16 + (l & 15);
      float bv = (MODE == 3) ? 0.f : bias[col];
#pragma unroll
      for (int j = 0; j < 4; ++j) {
        float v = acc[mr][nr][j] + bv;
        size_t off = (size_t)(rb + j) * ldc + col;
        if (MODE == 1) v = fmaxf(v, 0.f);
        Cbz[off] = f2bf(v);
      }
    }
  }
}

// ---------------- FF2 split-K=4 reduce (row-interleaved bf16 slices) ----------------
__global__ __launch_bounds__(256) void k_ff2_reduce(
    unsigned short* __restrict__ slices, const float* __restrict__ bias,
    const unsigned short* __restrict__ resid, float* __restrict__ partials) {
  __shared__ float red[8];
  int i = blockIdx.x;
  size_t rb = (size_t)i * 4096;
  int c = threadIdx.x * 4;
  u16x4 a0 = *(const u16x4*)(slices + rb + c);
  u16x4 a1 = *(const u16x4*)(slices + rb + 1024 + c);
  u16x4 a2 = *(const u16x4*)(slices + rb + 2048 + c);
  u16x4 a3 = *(const u16x4*)(slices + rb + 3072 + c);
  float4 bv = *(const float4*)(bias + c);
  u16x4 rv = *(const u16x4*)(resid + (size_t)i * 1024 + c);
  float4 o;
  o.x = bf2f(a0.x) + bf2f(a1.x) + bf2f(a2.x) + bf2f(a3.x) + bv.x + bf2f(rv.x);
  o.y = bf2f(a0.y) + bf2f(a1.y) + bf2f(a2.y) + bf2f(a3.y) + bv.y + bf2f(rv.y);
  o.z = bf2f(a0.z) + bf2f(a1.z) + bf2f(a2.z) + bf2f(a3.z) + bv.z + bf2f(rv.z);
  o.w = bf2f(a0.w) + bf2f(a1.w) + bf2f(a2.w) + bf2f(a3.w) + bv.w + bf2f(rv.w);
  __syncthreads();
  *(float4*)((float*)slices + (size_t)i * 2048 + c) = o;
  float bsum = o.x + o.y + o.z + o.w;
  float bsq = o.x * o.x + o.y * o.y + o.z * o.z + o.w * o.w;
  int wv = threadIdx.x >> 6, lv = threadIdx.x & 63;
#pragma unroll
  for (int mk = 1; mk < 64; mk <<= 1) { bsum += __shfl_xor(bsum, mk); bsq += __shfl_xor(bsq, mk); }
  if (lv == 0) { red[wv] = bsum; red[4 + wv] = bsq; }
  __syncthreads();
  if (threadIdx.x == 0) {
    partials[i * 2] = red[0] + red[1] + red[2] + red[3];
    partials[i * 2 + 1] = red[4] + red[5] + red[6] + red[7];
  }
}

// ---------------- causal flash attention, QBLK=128 (4 waves), 32x32 MFMA ----------------
// (round-17 state: deep K-prefetch before top wait; vmcnt(4) top; swapped QK,
// sigma-stored V, defer-max, log2-domain exp; qt-perm balances CU pairs.)
__global__ __launch_bounds__(256, 2) void k_attn(
    const unsigned short* __restrict__ Qg, const unsigned short* __restrict__ Kg,
    const unsigned short* __restrict__ Vt,
    const unsigned short* __restrict__ xbg, unsigned short* __restrict__ hpre,
    float* __restrict__ partials, int S, int H) {
  __shared__ __align__(16) unsigned short Ks[2][4096];
  __shared__ __align__(16) unsigned short Vs[2][4096];
  __shared__ float ascr[4][32];
  __shared__ float red[8];
  int bh = blockIdx.x, b = bh >> 4, h = bh & 15;
  int y = (int)blockIdx.y;
  int qt = (y < 8) ? (15 - y) : (y - 8);
  int tid = threadIdx.x, w = tid >> 6, l = tid & 63;
  int lo = l & 31, hi5 = l >> 5;
  const int U = H * 64;
  const unsigned short* Qb = Qg + (size_t)(b * S) * 1024 + h * 64;
  const unsigned short* Kb = Kg + (size_t)(b * S) * 1024 + h * 64;
  const unsigned short* Vb = Vt + (size_t)bh * 64 * S;
  int tl = 2 * qt + 1;

  int sg_r[2], sg_c[2];
#pragma unroll
  for (int it = 0; it < 2; ++it) {
    int g = it * 256 + tid;
    sg_r[it] = g >> 3;
    sg_c[it] = ((g & 7) ^ ((g >> 3) & 7)) * 8;
  }
#define STG_K(kt) do { int _kn = (kt) * 64, _bf = (kt) & 1; \
    _Pragma("unroll") for (int it = 0; it < 2; ++it) \
      GLDS16(Kb + (size_t)(_kn + sg_r[it]) * 1024 + sg_c[it], &Ks[_bf][(it * 256 + tid) * 8]); } while (0)
#define STG_V(kt) do { int _kn = (kt) * 64, _bf = (kt) & 1; \
    _Pragma("unroll") for (int it = 0; it < 2; ++it) \
      GLDS16(Vb + (size_t)sg_r[it] * S + _kn + sg_c[it], &Vs[_bf][(it * 256 + tid) * 8]); } while (0)

  int qrow = qt * 128 + w * 32 + lo;
  s16x8 qf[4];
#pragma unroll
  for (int s = 0; s < 4; ++s)
    qf[s] = *(const s16x8*)(Qb + (size_t)qrow * 1024 + s * 16 + hi5 * 8);

  int krow[16];
#pragma unroll
  for (int r = 0; r < 16; ++r) krow[r] = (r & 3) + 8 * (r >> 2) + 4 * hi5;
  int wq = w * 32 + lo;

  f32x16 o0 = {}, o1 = {};
  float m = -1e30f, lsum = 0.f;
  f32x16 scA0, scA1, scB0, scB1;

#define MBASE(T) (((T) >= 2 * qt) ? ((T) * 64 - qt * 128) : -1)

#define QK_T(S0, S1, T) do { \
    S0 = (f32x16)(0.0f); S1 = (f32x16)(0.0f); \
    const unsigned short* _kp = &Ks[(T) & 1][0]; \
    __builtin_amdgcn_s_setprio(1); \
    _Pragma("unroll") for (int s = 0; s < 4; ++s) { \
      int gc = ((2 * s + hi5) ^ (lo & 7)) * 8; \
      s16x8 kf0 = *(const s16x8*)&_kp[lo * 64 + gc]; \
      s16x8 kf1 = *(const s16x8*)&_kp[(32 + lo) * 64 + gc]; \
      S0 = MFMA32(kf0, qf[s], S0); \
      S1 = MFMA32(kf1, qf[s], S1); } \
    __builtin_amdgcn_s_setprio(0); } while (0)

#define SMPV(S0, S1, T, MB) do { \
    if ((MB) >= 0) { \
      _Pragma("unroll") for (int r = 0; r < 16; ++r) { \
        if (krow[r] + (MB) > wq) S0[r] = -1e30f; \
        if (krow[r] + 32 + (MB) > wq) S1[r] = -1e30f; } } \
    float mx = S0[0]; \
    _Pragma("unroll") for (int r = 1; r < 16; ++r) mx = fmaxf(mx, S0[r]); \
    _Pragma("unroll") for (int r = 0; r < 16; ++r) mx = fmaxf(mx, S1[r]); \
    mx = fmaxf(mx, __shfl_xor(mx, 32)); \
    if (__ballot(mx > m + 11.5415603f)) { \
      float mnew = fmaxf(m, mx); \
      float alpha = __builtin_amdgcn_exp2f(m - mnew); \
      m = mnew; lsum *= alpha; \
      if (l < 32) ascr[w][lo] = alpha; \
      _Pragma("unroll") for (int r = 0; r < 16; ++r) { \
        float aj = ascr[w][krow[r]]; o0[r] *= aj; o1[r] *= aj; } } \
    float rs = 0.f; unsigned wk0[8], wk1[8]; \
    _Pragma("unroll") for (int j = 0; j < 8; ++j) { \
      float p0 = __builtin_amdgcn_exp2f(S0[2 * j] - m); \
      float p1 = __builtin_amdgcn_exp2f(S0[2 * j + 1] - m); \
      rs += p0 + p1; wk0[j] = (unsigned)f2bf(p0) | ((unsigned)f2bf(p1) << 16); \
      float p2 = __builtin_amdgcn_exp2f(S1[2 * j] - m); \
      float p3 = __builtin_amdgcn_exp2f(S1[2 * j + 1] - m); \
      rs += p2 + p3; wk1[j] = (unsigned)f2bf(p2) | ((unsigned)f2bf(p3) << 16); } \
    rs += __shfl_xor(rs, 32); lsum += rs; \
    __builtin_amdgcn_s_setprio(1); \
    _Pragma("unroll") for (int s = 0; s < 4; ++s) { \
      u32x4 paw; \
      if (s == 0)      { paw.x = wk0[0]; paw.y = wk0[1]; paw.z = wk0[2]; paw.w = wk0[3]; } \
      else if (s == 1) { paw.x = wk0[4]; paw.y = wk0[5]; paw.z = wk0[6]; paw.w = wk0[7]; } \
      else if (s == 2) { paw.x = wk1[0]; paw.y = wk1[1]; paw.z = wk1[2]; paw.w = wk1[3]; } \
      else             { paw.x = wk1[4]; paw.y = wk1[5]; paw.z = wk1[6]; paw.w = wk1[7]; } \
      s16x8 pa = *(s16x8*)&paw; \
      int gc = ((2 * s + hi5) ^ (lo & 7)) * 8; \
      s16x8 vf0 = *(const s16x8*)&Vs[(T) & 1][lo * 64 + gc]; \
      s16x8 vf1 = *(const s16x8*)&Vs[(T) & 1][(32 + lo) * 64 + gc]; \
      o0 = MFMA32(pa, vf0, o0); \
      o1 = MFMA32(pa, vf1, o1); } \
    __builtin_amdgcn_s_setprio(0); \
  } while (0)

#define BODY(O0, O1, I0, I1, T) do { \
    if ((T) + 1 <= tl) STG_K((T) + 1); \
    asm volatile("s_waitcnt vmcnt(4)" ::: "memory"); \
    __builtin_amdgcn_s_barrier(); \
    __builtin_amdgcn_sched_barrier(0); \
    QK_T(O0, O1, (T)); \
    SMPV(I0, I1, (T) - 1, MBASE((T) - 1)); \
    asm volatile("s_waitcnt lgkmcnt(0)" ::: "memory"); \
    __builtin_amdgcn_sched_barrier(0); \
    __builtin_amdgcn_s_barrier(); \
    __builtin_amdgcn_sched_barrier(0); \
    if ((T) + 1 <= tl) STG_V((T) + 1); \
  } while (0)

  STG_K(0); STG_V(0); STG_K(1); STG_V(1);
  asm volatile("s_waitcnt vmcnt(4)" ::: "memory");
  __builtin_amdgcn_s_barrier();
  __builtin_amdgcn_sched_barrier(0);
  QK_T(scA0, scA1, 0);
  asm volatile("s_waitcnt lgkmcnt(0)" ::: "memory");
  __builtin_amdgcn_sched_barrier(0);

  int t = 1;
  for (; t + 1 <= tl; t += 2) {
    BODY(scB0, scB1, scA0, scA1, t);
    BODY(scA0, scA1, scB0, scB1, t + 1);
  }
  if (t <= tl) {
    BODY(scB0, scB1, scA0, scA1, t);
    asm volatile("s_waitcnt vmcnt(0)" ::: "memory");
    __builtin_amdgcn_sched_barrier(0);
    SMPV(scB0, scB1, tl, MBASE(tl));
  } else {
    asm volatile("s_waitcnt vmcnt(0)" ::: "memory");
    __builtin_amdgcn_sched_barrier(0);
    SMPV(scA0, scA1, tl, MBASE(tl));
  }

  // ---- epilogue: O/l + bf16 x residual -> bf16, LN partials ----
  if (l < 32) ascr[w][lo] = 1.f / lsum;
  float bsum = 0.f, bsq = 0.f;
  unsigned short* hb = hpre + (size_t)(b * S) * U + h * 64;
  const unsigned short* xb = xbg + (size_t)(b * S) * U + h * 64;
#pragma unroll
  for (int r = 0; r < 16; ++r) {
    float inv = ascr[w][krow[r]];
    int srow = qt * 128 + w * 32 + krow[r];
    size_t base = (size_t)srow * U + lo;
    float v0 = o0[r] * inv + bf2f(xb[base]);
    float v1 = o1[r] * inv + bf2f(xb[base + 32]);
    hb[base] = f2bf(v0);
    hb[base + 32] = f2bf(v1);
    bsum += v0 + v1; bsq += v0 * v0 + v1 * v1;
  }
#pragma unroll
  for (int mk = 1; mk < 64; mk <<= 1) { bsum += __shfl_xor(bsum, mk); bsq += __shfl_xor(bsq, mk); }
  if (l == 0) { red[w * 2] = bsum; red[w * 2 + 1] = bsq; }
  __syncthreads();
  if (tid == 0) {
    int pi = b * (H * 16) + h * 16 + qt;
    partials[pi * 2] = red[0] + red[2] + red[4] + red[6];
    partials[pi * 2 + 1] = red[1] + red[3] + red[5] + red[7];
  }
#undef STG_K
#undef STG_V
#undef QK_T
#undef SMPV
#undef BODY
#undef MBASE
}

// ---------------- LN over (S,U) per batch ----------------
__global__ __launch_bounds__(256) void k_ln_stats(const float* __restrict__ partials, int nper,
                                                  float* __restrict__ stats, float invN) {
  int b = blockIdx.x, tid = threadIdx.x;
  float s = 0.f, q = 0.f;
  for (int i = tid; i < nper; i += 256) { s += partials[(b * nper + i) * 2]; q += partials[(b * nper + i) * 2 + 1]; }
#pragma unroll
  for (int mk = 1; mk < 64; mk <<= 1) { s += __shfl_xor(s, mk); q += __shfl_xor(q, mk); }
  __shared__ float red[8];
  int w = tid >> 6, l = tid & 63;
  if (l == 0) { red[w] = s; red[4 + w] = q; }
  __syncthreads();
  if (tid == 0) {
    s = red[0] + red[1] + red[2] + red[3];
    q = red[4] + red[5] + red[6] + red[7];
    float m = s * invN, var = q * invN - m * m;
    stats[b * 2] = m; stats[b * 2 + 1] = rsqrtf(var + 1e-5f);
  }
}

// LN apply from bf16 src -> bf16 out (LN1 path)
__global__ __launch_bounds__(256) void k_ln_apply_b(
    const unsigned short* __restrict__ src, const float* __restrict__ stats,
    const float* __restrict__ g, const float* __restrict__ bt,
    unsigned short* __restrict__ outb, int SU) {
  int b = blockIdx.y;
  int idx = (blockIdx.x * 256 + threadIdx.x) * 4;
  float m = stats[b * 2], r = stats[b * 2 + 1];
  u16x4 v4 = *(const u16x4*)(src + (size_t)b * SU + idx);
  float4 gg = *(const float4*)(g + idx);
  float4 bb = *(const float4*)(bt + idx);
  u16x4 ob;
  ob.x = f2bf((bf2f(v4.x) - m) * r * gg.x + bb.x);
  ob.y = f2bf((bf2f(v4.y) - m) * r * gg.y + bb.y);
  ob.z = f2bf((bf2f(v4.z) - m) * r * gg.z + bb.z);
  ob.w = f2bf((bf2f(v4.w) - m) * r * gg.w + bb.w);
  *(u16x4*)(outb + (size_t)b * SU + idx) = ob;
}

// LN apply from stride-2048 f32 rows (FF2 reduce output) -> d_out
__global__ __launch_bounds__(256) void k_ln_apply2(
    const float* __restrict__ src, const float* __restrict__ stats,
    const float* __restrict__ g, const float* __restrict__ bt,
    float* __restrict__ outf) {
  int b = blockIdx.y;
  int row = blockIdx.x;
  int grow = b * 2048 + row;
  int c = threadIdx.x * 4;
  float m = stats[b * 2], r = stats[b * 2 + 1];
  float4 v = *(const float4*)(src + (size_t)grow * 2048 + c);
  float4 gg = *(const float4*)(g + (size_t)row * 1024 + c);
  float4 bb = *(const float4*)(bt + (size_t)row * 1024 + c);
  float4 o;
  o.x = (v.x - m) * r * gg.x + bb.x;
  o.y = (v.y - m) * r * gg.y + bb.y;
  o.z = (v.z - m) * r * gg.z + bb.z;
  o.w = (v.w - m) * r * gg.w + bb.w;
  *(float4*)(outf + (size_t)grow * 1024 + c) = o;
}

extern "C" void kernel_launch(void* const* d_in, const int* in_sizes, int n_in,
                              void* d_out, int out_size, void* d_ws, size_t ws_size,
                              hipStream_t stream) {
  (void)in_sizes; (void)n_in; (void)out_size; (void)ws_size;
  const int S = 2048, H = 16;
  const float* x   = (const float*)d_in[0];
  const float* wq  = (const float*)d_in[1];
  const float* bq  = (const float*)d_in[2];
  const float* wk  = (const float*)d_in[3];
  const float* bk  = (const float*)d_in[4];
  const float* wv  = (const float*)d_in[5];
  const float* bv  = (const float*)d_in[6];
  const float* wf1 = (const float*)d_in[7];
  const float* bf1 = (const float*)d_in[8];
  const float* wf2 = (const float*)d_in[9];
  const float* bf2 = (const float*)d_in[10];
  const float* lng = (const float*)d_in[11];
  const float* lnb = (const float*)d_in[12];
  const float* ffg = (const float*)d_in[13];
  const float* ffb = (const float*)d_in[14];

  char* ws = (char*)d_ws;
  unsigned short* wqkvT = (unsigned short*)(ws);              // 3072x1024 bf16 (dead after QKV)
  unsigned short* wf1T  = (unsigned short*)(ws + 6291456);    // 4096x1024 bf16 (dead after FF1)
  unsigned short* wf2T  = (unsigned short*)(ws + 14680064);   // 1024x4096 bf16
  unsigned short* xb    = (unsigned short*)(ws + 23068672);   // 4096x1024 bf16 (live through attn)
  unsigned short* qb    = (unsigned short*)(ws + 31457280);   // 4096x1024 bf16 Q (dead after attn)
  unsigned short* kbuf  = (unsigned short*)(ws + 39845888);   // 4096x1024 bf16 K (dead after attn)
  unsigned short* vt    = (unsigned short*)(ws + 56623104);   // 32x64x2048 bf16 V^T sigma (dead after attn)
  unsigned short* h1b   = (unsigned short*)(ws + 65011712);   // 4096x1024 bf16 (LN1 out)
  unsigned short* hpreb = (unsigned short*)(ws + 73400320);   // 4096x1024 bf16 (attn out, dead after LN1)
  unsigned short* ff2s  = (unsigned short*)(ws + 73400320);   // FF2 slices: 4096x4096 bf16 (over hpreb)
  unsigned short* f1b   = (unsigned short*)(ws + 23068672);   // 4096x4096 bf16 (over xb+qb+kbuf)
  float* biasqkv        = (float*)(ws + 106954752);           // 3072 f32
  float* part_attn      = (float*)(ws + 106967040);           // 2*256*2 f32
  float* stats1         = (float*)(ws + 106977280);           // 2*2 f32
  float* ffpart2        = (float*)(ws);                       // 4096*2 f32 (over wqkvT, dead)
  float* stats2         = (float*)(ws + 65536);               // 2*2 f32 (over wqkvT, dead)

  // Q path pre-scaled by 0.125 * log2(e) for log2-domain softmax
  const float qscale = 0.125f * 1.44269504f;

  // fused preprocessing: 1 launch instead of 5
  k_prep<<<6924, 256, 0, stream>>>(x, xb, wq, wk, wv, wqkvT, wf1, wf1T, wf2, wf2T,
                                   bq, bk, bv, biasqkv, qscale);

  // QKV projection: split outputs Q | K | V^T(sigma) (no separate transpose pass)
  k_gemm8<4><<<dim3(192, 1, 1), 512, 0, stream>>>(xb, 1024, wqkvT, 1024, biasqkv,
      nullptr, nullptr, 0, 1024, 12, 0, qb, kbuf, vt);

  // causal flash attention (QBLK=128, 4 waves) + bf16 x residual -> bf16 + LN1 partials
  k_attn<<<dim3(32, 16), 256, 0, stream>>>(qb, kbuf, vt, xb, hpreb, part_attn, S, H);

  // LN1 -> bf16
  k_ln_stats<<<2, 256, 0, stream>>>(part_attn, 256, stats1, 1.f / (2048.f * 1024.f));
  k_ln_apply_b<<<dim3(2048, 2), 256, 0, stream>>>(hpreb, stats1, lng, lnb, h1b, S * 1024);

  // FF1: (4096x1024) @ (1024x4096), ReLU
  k_gemm8<1><<<dim3(256, 1, 1), 512, 0, stream>>>(h1b, 1024, wf1T, 1024, bf1,
      f1b, nullptr, 4096, 1024, 16, 0, nullptr, nullptr, nullptr);

  // FF2: (4096x4096) @ (4096x1024), split-K=4, bf16 row-interleaved slices
  k_gemm8<3><<<dim3(64, 1, 4), 512, 0, stream>>>(f1b, 4096, wf2T, 4096, nullptr,
      ff2s, nullptr, 4096, 1024, 4, 1024, nullptr, nullptr, nullptr);

  // reduce slices + bias + bf16 residual -> f32 rows (stride 2048), LN2 partials
  k_ff2_reduce<<<4096, 256, 0, stream>>>(ff2s, bf2, h1b, ffpart2);

  // LN2 -> d_out (fp32)
  k_ln_stats<<<2, 256, 0, stream>>>(ffpart2, 2048, stats2, 1.f / (2048.f * 1024.f));
  k_ln_apply2<<<dim3(2048, 2), 256, 0, stream>>>((float*)ff2s, stats2, ffg, ffb, (float*)d_out);
}